// Round 4
// baseline (811.615 us; speedup 1.0000x reference)
//
#include <hip/hip_runtime.h>
#include <math.h>
#include <stdint.h>

// ConvLSTM (Seq2VecRNN2D) round 9: N=64 blocks (G-quarter) to halve per-CU W-DMA,
// taller M per block, m=2 wave tiles (2 rows x 32 px x 64 N, 16 reads : 48 MFMA).
//   Paired <ROWS=8,NW=4>: 8b x 4band x 4Q x z2 = 256 blocks, 256 thr, LDS 112 KB.
//   Solo   <ROWS=4,NW=2>: 8b x 8band x 4Q      = 256 blocks, 128 thr, LDS 76 KB.
// Round-0 proven barrier discipline: tap-granularity, W triple-buffer (8 KB tiles),
// counted vmcnt (no drains in loop). 3-term bf16-split MFMA, fused LSTM cell.
// B=8 T=8 CIN=128 HID=64 G=256 H=W=32.
//
// Activation image per (slot,b,cg32): [34 y'][34 px][8 blk of 16B], blk = pl*4+kg
// stored at blk^(px&7); ch = cg*32+kg*8+j, pl0=hi bf16, pl1=lo bf16. Borders zero.
// Weight image per (combo,cg,tap,nt): [pl][4 g][16 hcp][8 b8 of 16B], b8 = kg+4*(hc&1)
// stored at b8^(hcp&7); hcp = hc_local>>1. A block stages the nq-half of an nt tile:
// 8 chunks of 1 KB at src stride 2 KB (chunk c = pl*4+g, + nq*1024).
//
// vmcnt (per-wave queue sim, in-order retirement):
//   prologue A0(ACH), W0(WCH), W1(WCH)
//   tap0 & taps>=3: vmcnt(WCH);  taps 1,2: vmcnt(WCH+ACH)
//   paired: 2 / 13     solo: 4 / 17

typedef __attribute__((ext_vector_type(8))) short short8;
typedef __attribute__((ext_vector_type(4))) float float4v;

namespace {
constexpr int IMG = 34 * 34 * 64;            // u16 per (slot,b,cg) image
constexpr size_t SLOTI = 16ull * IMG;        // u16 per h slot (8 b x 2 cg)
constexpr int ROWB = 34 * 128;               // bytes per image row (4352)
constexpr int PADB = 8192;                   // tail slack for DMA overshoot
}
template <int N> struct IC { static constexpr int v = N; };

__device__ __forceinline__ uint16_t bf16_rne(float x) {
  uint32_t u = __builtin_bit_cast(uint32_t, x);
  return (uint16_t)((u + 0x7FFFu + ((u >> 16) & 1u)) >> 16);
}
__device__ __forceinline__ float bf16_to_f(uint16_t h) {
  uint32_t u = ((uint32_t)h) << 16;
  return __builtin_bit_cast(float, u);
}

__device__ __forceinline__ void gl_lds16(const void* g, void* l) {
  __builtin_amdgcn_global_load_lds(
      (const __attribute__((address_space(1))) void*)g,
      (__attribute__((address_space(3))) void*)l, 16, 0, 0);
}

// ---- feature pack: fp32 [B][T][128][32][32] -> swizzled images [t][b][4cg] ----
__global__ void pack_features(const float* __restrict__ f, uint16_t* __restrict__ out) {
  const size_t i = (size_t)blockIdx.x * 256 + threadIdx.x;  // 16B-block index, < 2367488
  const int blk_s = (int)(i & 7);
  size_t pp = i >> 3;
  const int px = (int)(pp % 34); pp /= 34;
  const int yy = (int)(pp % 34); pp /= 34;
  const int cg = (int)(pp & 3);
  const int bt = (int)(pp >> 2);
  const int b = bt & 7, t = bt >> 3;
  const int blk = blk_s ^ (px & 7);
  const int pl = blk >> 2, kg = blk & 3;
  short8 sv;
  if (px == 0 || px == 33 || yy == 0 || yy == 33) {
    #pragma unroll
    for (int j = 0; j < 8; ++j) sv[j] = 0;
  } else {
    const int x = px - 1, y = yy - 1;
    #pragma unroll
    for (int j = 0; j < 8; ++j) {
      const int ch = cg * 32 + kg * 8 + j;
      const float fv = f[(((size_t)b * 8 + t) * 128 + ch) * 1024 + y * 32 + x];
      const uint16_t hi = bf16_rne(fv);
      sv[j] = (short)(pl ? bf16_rne(fv - bf16_to_f(hi)) : hi);
    }
  }
  *(short8*)(out + i * 8) = sv;
}

// ---- weight pack into swizzled images: per combo [cg][tap][nt][4096 u32] ----
struct WPackArgs {
  const float* wih[4]; const float* whh[4];
  const float* bih[4]; const float* bhh[4];
  uint32_t* wp; float* bp;
};
__global__ void pack_weights(WPackArgs A) {
  const int combo = blockIdx.y;
  const int idx = blockIdx.x * 256 + threadIdx.x;  // < 442368
  const int q = idx & 4095;
  const int rest = idx >> 12;
  const int nt = rest & 1;
  const int ct = rest >> 1;          // cg*9+tap
  const int tap = ct % 9, cg = ct / 9;
  const int w2 = q & 3;
  const int b8s = (q >> 2) & 7;
  const int hcp = (q >> 5) & 15;
  const int g = (q >> 9) & 3;
  const int pl = (q >> 11) & 1;
  const int b8 = b8s ^ (hcp & 7);
  const int kg = b8 & 3;
  const int hcl = hcp * 2 + (b8 >> 2);
  const int n = g * 64 + nt * 32 + hcl;
  const float* wih = A.wih[combo];
  const float* whh = A.whh[combo];
  uint32_t out = 0;
  #pragma unroll
  for (int e = 0; e < 2; ++e) {
    const int ch = cg * 32 + kg * 8 + w2 * 2 + e;
    const float wv = (ch < 128) ? wih[((size_t)n * 128 + ch) * 9 + tap]
                                : whh[((size_t)n * 64 + (ch - 128)) * 9 + tap];
    const uint16_t hi = bf16_rne(wv);
    const uint16_t v = pl ? bf16_rne(wv - bf16_to_f(hi)) : hi;
    out |= ((uint32_t)v) << (16 * e);
  }
  A.wp[(size_t)combo * 442368 + idx] = out;
  if (idx < 256) A.bp[combo * 256 + idx] = A.bih[combo][idx] + A.bhh[combo][idx];
}

struct StepArgs {
  const uint16_t* in0; const uint16_t* in1; const uint16_t* in2;  // images
  int nc0, nc1, nc2;         // cg counts per tensor
  const uint32_t* W;         // combo base: [cg][tap][nt][4096 u32]
  const float* bias;         // [256], n = gate*64+hc
  float* cbuf;               // plain fp32 [b][64][1024]
  uint16_t* himg;            // nullable: [b][2 cg][IMG]
  float* hf32;               // nullable: plain [b][64][1024]
};

// Block: Q4 = bx&3 (G-quarter: nt = Q4>>1 tile, nq = Q4&1 hcp-half), band, b.
// NW waves; wave w owns rows {2w, 2w+1} and the FULL block N=64 (4 g x 16 hc).
// Per wave per tap: 8 A frags + 8 W frags (16 ds_read_b128), 48 MFMA.
template <int ROWS, int NW>
__global__ __launch_bounds__(NW * 64, 1) void conv_lstm_step(StepArgs A0, StepArgs A1) {
  constexpr int THREADS = NW * 64;
  constexpr int BANDS = 32 / ROWS;
  constexpr int BSH = (ROWS == 8) ? 2 : 3;     // log2(BANDS)
  constexpr int ABYTES = (ROWS + 2) * ROWB;
  constexpr int ACH = (ABYTES + NW * 1024 - 1) / (NW * 1024);  // A chunks per wave
  constexpr int ASLOT = ACH * NW * 1024;
  constexpr int WCH = 8 / NW;                  // W chunks per wave (8 KB tile)
  constexpr int CNT0 = WCH;                    // taps 0, >=3
  constexpr int CNT12 = WCH + ACH;             // taps 1,2

  extern __shared__ char smem[];
  char* Asm_ = smem;                           // 2 x ASLOT (A double-buffer)
  char* Wsm_ = smem + 2 * ASLOT;               // 3 x 8192 (W triple-buffer)

  const StepArgs a = (blockIdx.z == 0) ? A0 : A1;
  const int bx = blockIdx.x;
  const int Q4 = bx & 3;
  const int band = (bx >> 2) & (BANDS - 1);
  const int b = bx >> (2 + BSH);
  const int nt = Q4 >> 1;
  const int nq = Q4 & 1;
  const int y0 = band * ROWS;
  const int tid = threadIdx.x;
  const int lane = tid & 63;
  const int w = tid >> 6;
  const int m15 = lane & 15;
  const int kg = lane >> 4;

  // fragment read offsets (bytes), conflict-free via baked swizzle
  int offA[2][2][3][2];   // [row][xh][kx][pl]
  #pragma unroll
  for (int row = 0; row < 2; ++row)
    #pragma unroll
    for (int xh = 0; xh < 2; ++xh)
      #pragma unroll
      for (int kx = 0; kx < 3; ++kx)
        #pragma unroll
        for (int pl = 0; pl < 2; ++pl) {
          const int px = xh * 16 + kx + m15;
          const int sw = (pl * 4 + kg) ^ (px & 7);
          offA[row][xh][kx][pl] = (2 * w + row) * ROWB + px * 128 + sw * 16;
        }
  int offW[2][4];
  {
    const int hcpl = m15 >> 1;                 // local hcp 0..7
    const int b8 = kg + 4 * (m15 & 1);
    #pragma unroll
    for (int pl = 0; pl < 2; ++pl)
      #pragma unroll
      for (int g = 0; g < 4; ++g)
        offW[pl][g] = (((pl * 4 + g) * 8 + hcpl) * 8 + (b8 ^ hcpl)) * 16;
  }

  const int ncg = a.nc0 + a.nc1 + a.nc2;
  auto abase = [&](int cg) -> const char* {
    const uint16_t* t;
    if (cg < a.nc0) t = a.in0 + ((size_t)b * a.nc0 + cg) * IMG;
    else if (cg < a.nc0 + a.nc1) t = a.in1 + ((size_t)b * a.nc1 + (cg - a.nc0)) * IMG;
    else t = a.in2 + ((size_t)b * a.nc2 + (cg - a.nc0 - a.nc1)) * IMG;
    return (const char*)t + (size_t)y0 * ROWB;
  };
  // ACH chunks/wave (ROWS+2 rows used; slot tail dead; source has PADB slack)
  auto stageA = [&](int cgi, int par) {
    const char* g = abase(cgi);
    char* d = Asm_ + par * ASLOT;
    #pragma unroll
    for (int j = 0; j < ACH; ++j)
      gl_lds16(g + (size_t)(ACH * w + j) * 1024 + lane * 16, d + (ACH * w + j) * 1024);
  };
  // nq-half of an nt W tile: 8 x 1 KB chunks, src stride 2 KB (chunk c = pl*4+g)
  auto stageW = [&](int cgs, int taps, int slot) {
    const char* g = (const char*)a.W + ((size_t)((cgs * 9 + taps) * 2 + nt) << 14)
                  + (size_t)nq * 1024;
    char* d = Wsm_ + slot * 8192;
    #pragma unroll
    for (int j = 0; j < WCH; ++j) {
      const int c = WCH * w + j;
      gl_lds16(g + (size_t)c * 2048 + lane * 16, d + c * 1024);
    }
  };

  float4v acc[2][2][4];   // [row][xh][g]
  #pragma unroll
  for (int row = 0; row < 2; ++row)
    #pragma unroll
    for (int xh = 0; xh < 2; ++xh)
      #pragma unroll
      for (int g = 0; g < 4; ++g) acc[row][xh][g] = (float4v){0.f, 0.f, 0.f, 0.f};

  // Prologue: A[0] then W[0,0], W[0,1] (order matters for vmcnt math).
  stageA(0, 0);
  stageW(0, 0, 0);
  stageW(0, 1, 1);

  for (int cg = 0; cg < ncg; ++cg) {
    auto tap_body = [&](auto tapc) {
      constexpr int TAP = decltype(tapc)::v;
      constexpr int CNT = (TAP == 1 || TAP == 2) ? CNT12 : CNT0;
      asm volatile("s_waitcnt vmcnt(%0)\n\ts_barrier" :: "n"(CNT) : "memory");
      const int lin = cg * 9 + TAP;
      {  // stage W for lin+2 (wrap to a dead-but-valid tile near the end)
        const int l2 = lin + 2;
        int cgs = l2 / 9;
        const int taps = l2 % 9;
        if (cgs >= ncg) cgs = 0;
        stageW(cgs, taps, l2 % 3);
      }
      if (TAP == 0) {  // stage next cg's A into the other parity
        const int nx = (cg + 1 < ncg) ? cg + 1 : 0;
        stageA(nx, (cg + 1) & 1);
      }
      constexpr int ky = TAP / 3, kx = TAP % 3;
      const char* Ab = Asm_ + (cg & 1) * ASLOT + ky * ROWB;
      const char* Wb = Wsm_ + (lin % 3) * 8192;
      short8 af[2][2][2];   // [row][xh][pl]
      #pragma unroll
      for (int row = 0; row < 2; ++row)
        #pragma unroll
        for (int xh = 0; xh < 2; ++xh)
          #pragma unroll
          for (int pl = 0; pl < 2; ++pl)
            af[row][xh][pl] = *(const short8*)(Ab + offA[row][xh][kx][pl]);
      short8 wfr[2][4];
      #pragma unroll
      for (int pl = 0; pl < 2; ++pl)
        #pragma unroll
        for (int g = 0; g < 4; ++g)
          wfr[pl][g] = *(const short8*)(Wb + offW[pl][g]);
      #pragma unroll
      for (int row = 0; row < 2; ++row)
        #pragma unroll
        for (int xh = 0; xh < 2; ++xh)
          #pragma unroll
          for (int g = 0; g < 4; ++g) {
            acc[row][xh][g] = __builtin_amdgcn_mfma_f32_16x16x32_bf16(af[row][xh][0], wfr[0][g], acc[row][xh][g], 0, 0, 0);
            acc[row][xh][g] = __builtin_amdgcn_mfma_f32_16x16x32_bf16(af[row][xh][0], wfr[1][g], acc[row][xh][g], 0, 0, 0);
            acc[row][xh][g] = __builtin_amdgcn_mfma_f32_16x16x32_bf16(af[row][xh][1], wfr[0][g], acc[row][xh][g], 0, 0, 0);
          }
    };
    tap_body(IC<0>{}); tap_body(IC<1>{}); tap_body(IC<2>{});
    tap_body(IC<3>{}); tap_body(IC<4>{}); tap_body(IC<5>{});
    tap_body(IC<6>{}); tap_body(IC<7>{}); tap_body(IC<8>{});
  }
  asm volatile("s_waitcnt vmcnt(0)" ::: "memory");  // drain dummy restages

  // ---- fused LSTM cell epilogue ----
  const int hc = Q4 * 16 + m15;                // global hidden channel 0..63
  float bi[4];
  #pragma unroll
  for (int g = 0; g < 4; ++g) bi[g] = a.bias[g * 64 + hc];
  const int img = Q4 >> 1;                     // which 32-ch h image
  const int chi = (Q4 & 1) * 16 + m15;         // channel within image 0..31
  const int kgb = chi >> 3, jj = chi & 7;
  uint16_t* hb = a.himg ? a.himg + ((size_t)(b * 2 + img)) * IMG : nullptr;
  #pragma unroll
  for (int row = 0; row < 2; ++row) {
    const int y = y0 + 2 * w + row;
    float* crow = a.cbuf + ((size_t)(b * 64 + hc)) * 1024 + y * 32;
    float* hrow = a.hf32 ? a.hf32 + ((size_t)(b * 64 + hc)) * 1024 + y * 32 : nullptr;
    #pragma unroll
    for (int xh = 0; xh < 2; ++xh) {
      const int x0 = xh * 16 + kg * 4;
      float4v cv = *(float4v*)(crow + x0);
      float4v cn, hn;
      #pragma unroll
      for (int q = 0; q < 4; ++q) {
        const float ig = 1.f / (1.f + expf(-(acc[row][xh][0][q] + bi[0])));
        const float fg = 1.f / (1.f + expf(-(acc[row][xh][1][q] + bi[1])));
        const float gg = tanhf(acc[row][xh][2][q] + bi[2]);
        const float og = 1.f / (1.f + expf(-(acc[row][xh][3][q] + bi[3])));
        const float c2 = fg * cv[q] + ig * gg;
        cn[q] = c2;
        hn[q] = og * tanhf(c2);
      }
      *(float4v*)(crow + x0) = cn;
      if (hrow) *(float4v*)(hrow + x0) = hn;
      if (hb) {
        #pragma unroll
        for (int q = 0; q < 4; ++q) {
          const int px = x0 + q + 1;
          const int sw = px & 7;
          const uint16_t hi = bf16_rne(hn[q]);
          const uint16_t lo = bf16_rne(hn[q] - bf16_to_f(hi));
          const size_t p16 = ((size_t)(y + 1) * 34 + px) * 64;
          hb[p16 + (size_t)(kgb ^ sw) * 8 + jj] = hi;
          hb[p16 + (size_t)((4 + kgb) ^ sw) * 8 + jj] = lo;
        }
      }
    }
  }
  if (hb) {   // keep image borders zero (ws is re-poisoned every call)
    for (int i = tid; i < ROWS * 128; i += THREADS) {
      const int rr = i >> 7;
      const int hlf = (i >> 6) & 1;
      const int jx = i & 63;
      hb[((size_t)(y0 + 1 + rr) * 34 + hlf * 33) * 64 + jx] = 0;
    }
    if (band == 0) for (int i = tid; i < 2176; i += THREADS) hb[i] = 0;
    if (band == BANDS - 1) for (int i = tid; i < 2176; i += THREADS) hb[(size_t)33 * 2176 + i] = 0;
  }
}

// out[b][o][p] = relu(b_out[o] + sum_c w_out[o][c] * last[b][c][p])  (fp32 inputs)
__global__ void final_conv(const float* __restrict__ h1f_last, const float* __restrict__ h1r_last,
                           const float* __restrict__ wout, const float* __restrict__ bout,
                           float* __restrict__ out) {
  __shared__ float Ws[16 * 128];
  const int oq = blockIdx.y;
  for (int i = threadIdx.x; i < 16 * 128; i += 256) Ws[i] = wout[oq * 16 * 128 + i];
  __syncthreads();
  const int gp = blockIdx.x * 256 + threadIdx.x;
  const int b = gp >> 10, p = gp & 1023;
  float acc[16];
  #pragma unroll
  for (int o = 0; o < 16; ++o) acc[o] = bout[oq * 16 + o];
  for (int c = 0; c < 128; ++c) {
    const float xv = (c < 64) ? h1f_last[((size_t)b * 64 + c) * 1024 + p]
                              : h1r_last[((size_t)b * 64 + (c - 64)) * 1024 + p];
    #pragma unroll
    for (int o = 0; o < 16; ++o) acc[o] = fmaf(xv, Ws[o * 128 + c], acc[o]);
  }
  #pragma unroll
  for (int o = 0; o < 16; ++o) {
    const float v = acc[o];
    out[((size_t)b * 64 + oq * 16 + o) * 1024 + p] = v > 0.f ? v : 0.f;
  }
}

extern "C" void kernel_launch(void* const* d_in, const int* in_sizes, int n_in,
                              void* d_out, int out_size, void* d_ws, size_t ws_size,
                              hipStream_t stream) {
  char* p = (char*)d_ws;
  uint16_t* featImg = (uint16_t*)p; p += (size_t)8 * 8 * 4 * IMG * 2 + PADB;  // 37.9 MB
  uint32_t* WP = (uint32_t*)p;      p += (size_t)4 * 442368 * 4;              // 7.1 MB
  float* bp = (float*)p;            p += 4096;
  uint16_t* hf0i = (uint16_t*)p;    p += (size_t)9 * SLOTI * 2 + PADB;        // 21.3 MB
  uint16_t* hr0i = (uint16_t*)p;    p += (size_t)9 * SLOTI * 2 + PADB;        // 21.3 MB
  uint16_t* h1fi = (uint16_t*)p;    p += (size_t)2 * SLOTI * 2 + PADB;        // 4.7 MB
  float* c0f = (float*)p;           p += (size_t)4 * 2097152;                 // c states
  float* c0r = c0f + 524288;
  float* c1f = c0r + 524288;
  float* c1r = c1f + 524288;
  float* h1f8 = (float*)p;          p += 2097152;
  float* h1r8 = (float*)p;          p += 2097152;

  hipMemsetAsync(c0f, 0, (size_t)4 * 2097152, stream);
  hipMemsetAsync(hf0i, 0, (size_t)SLOTI * 2, stream);                     // hf0 slot 0
  hipMemsetAsync(hr0i + (size_t)8 * SLOTI, 0, (size_t)SLOTI * 2, stream); // hr0 slot 8
  hipMemsetAsync(h1fi, 0, (size_t)SLOTI * 2, stream);                     // h1f parity-0 slot

  pack_features<<<dim3(9248), 256, 0, stream>>>((const float*)d_in[0], featImg);

  WPackArgs wa;
  for (int combo = 0; combo < 4; ++combo) {
    const int base = 1 + combo * 4;
    wa.wih[combo] = (const float*)d_in[base];
    wa.whh[combo] = (const float*)d_in[base + 1];
    wa.bih[combo] = (const float*)d_in[base + 2];
    wa.bhh[combo] = (const float*)d_in[base + 3];
  }
  wa.wp = WP; wa.bp = bp;
  pack_weights<<<dim3(1728, 4), 256, 0, stream>>>(wa);

  // Paired <8,4>: ASLOT = 11*4*1024 = 45056; LDS = 2*45056 + 3*8192 = 114688.
  // Solo   <4,2>: ASLOT = 13*2*1024 = 26624; LDS = 2*26624 + 3*8192 = 77824.
  constexpr int DYN_P = 2 * 45056 + 3 * 8192;
  constexpr int DYN_S = 2 * 26624 + 3 * 8192;
  (void)hipFuncSetAttribute((const void*)(conv_lstm_step<8, 4>),
                            hipFuncAttributeMaxDynamicSharedMemorySize, DYN_P);
  (void)hipFuncSetAttribute((const void*)(conv_lstm_step<4, 2>),
                            hipFuncAttributeMaxDynamicSharedMemorySize, DYN_S);

  auto mk = [&](const uint16_t* i0, int n0, const uint16_t* i1, int n1,
                const uint16_t* i2, int n2, int combo, float* cb,
                uint16_t* himg, float* hf32) {
    StepArgs s;
    s.in0 = i0; s.in1 = i1; s.in2 = i2;
    s.nc0 = n0; s.nc1 = n1; s.nc2 = n2;
    s.W = WP + (size_t)combo * 442368; s.bias = bp + combo * 256;
    s.cbuf = cb; s.himg = himg; s.hf32 = hf32;
    return s;
  };

  // Layer 0: 8 pair launches (fwd step k, rev step 7-k); 128 blocks/dir x z=2.
  for (int k = 0; k < 8; ++k) {
    const int tr = 7 - k;
    StepArgs f = mk(featImg + (size_t)k * 8 * 4 * IMG, 4,
                    hf0i + (size_t)k * SLOTI, 2, nullptr, 0,
                    0, c0f, hf0i + (size_t)(k + 1) * SLOTI, nullptr);
    StepArgs r = mk(featImg + (size_t)tr * 8 * 4 * IMG, 4,
                    hr0i + (size_t)(tr + 1) * SLOTI, 2, nullptr, 0,
                    1, c0r, hr0i + (size_t)tr * SLOTI, nullptr);
    conv_lstm_step<8, 4><<<dim3(128, 1, 2), 256, DYN_P, stream>>>(f, r);
  }

  // Layer 1: fwd t=0 pairs with the single reverse step (t=7, zero init state).
  // Solo steps t=1..7: <4,2> at 256 blocks (full GPU), 128 thr.
  for (int t = 0; t < 8; ++t) {
    uint16_t* himg = (t < 7) ? h1fi + (size_t)((t + 1) & 1) * SLOTI : nullptr;
    float* hf32 = (t == 7) ? h1f8 : nullptr;
    StepArgs s = mk(hf0i + (size_t)(t + 1) * SLOTI, 2, hr0i + (size_t)t * SLOTI, 2,
                    h1fi + (size_t)(t & 1) * SLOTI, 2, 2, c1f, himg, hf32);
    if (t == 0) {
      StepArgs rv = mk(hf0i + (size_t)8 * SLOTI, 2, hr0i + (size_t)7 * SLOTI, 2,
                       nullptr, 0, 3, c1r, nullptr, h1r8);
      conv_lstm_step<8, 4><<<dim3(128, 1, 2), 256, DYN_P, stream>>>(s, rv);
    } else {
      conv_lstm_step<4, 2><<<dim3(256, 1, 1), 128, DYN_S, stream>>>(s, s);
    }
  }

  final_conv<<<dim3(32, 4), 256, 0, stream>>>(
      h1f8, h1r8, (const float*)d_in[17], (const float*)d_in[18], (float*)d_out);
}

// Round 5
// 742.795 us; speedup vs baseline: 1.0927x; 1.0927x over previous
//
#include <hip/hip_runtime.h>
#include <math.h>
#include <stdint.h>

// ConvLSTM (Seq2VecRNN2D) round 10: TWO independent 4-wave blocks per CU so the
// two blocks' read/MFMA phases interleave (break barrier lockstep). Per-block
// schedule = round-0 proven (tap granularity, W triple-buffer 8 KB tiles, counted
// vmcnt, synchronous fragment reads). N=64 per block (G-quarter Q4).
//   Paired <ROWS=4,NW=4,MT=2>: 8b x 8band x 4Q x z2 = 512 blocks, 256 thr,
//     LDS 81920/block (2 x 163840 = full 160 KiB/CU). Wave = 1 row x 64 N.
//   Solo   <ROWS=2,NW=4,MT=1>: 8b x 16band x 4Q     = 512 blocks, 256 thr,
//     LDS 65536/block. Wave = 1 Mtile (16 px) x 64 N.
// 3-term bf16-split MFMA, fused LSTM cell. B=8 T=8 CIN=128 HID=64 G=256 H=W=32.
//
// Activation image per (slot,b,cg32): [34 y'][34 px][8 blk of 16B], blk = pl*4+kg
// stored at blk^(px&7); ch = cg*32+kg*8+j, pl0=hi bf16, pl1=lo bf16. Borders zero.
// Weight image per (combo,cg,tap,nt): [pl][4 g][16 hcp][8 b8 of 16B], b8 = kg+4*(hc&1)
// stored at b8^(hcp&7); hcp = hc_local>>1. A block stages the nq-half of an nt tile:
// 8 chunks of 1 KB at src stride 2 KB (chunk c = pl*4+g).
//
// vmcnt (per-wave queue sim, in-order retirement):
//   prologue A0(ACH), W0(WCH=2), W1(WCH)
//   taps 0 and >=3: vmcnt(WCH)=2;  taps 1,2: vmcnt(WCH+ACH) -> paired 9, solo 7.

typedef __attribute__((ext_vector_type(8))) short short8;
typedef __attribute__((ext_vector_type(4))) float float4v;

namespace {
constexpr int IMG = 34 * 34 * 64;            // u16 per (slot,b,cg) image
constexpr size_t SLOTI = 16ull * IMG;        // u16 per h slot (8 b x 2 cg)
constexpr int ROWB = 34 * 128;               // bytes per image row (4352)
constexpr int PADB = 8192;                   // tail slack for DMA overshoot
}
template <int N> struct IC { static constexpr int v = N; };

__device__ __forceinline__ uint16_t bf16_rne(float x) {
  uint32_t u = __builtin_bit_cast(uint32_t, x);
  return (uint16_t)((u + 0x7FFFu + ((u >> 16) & 1u)) >> 16);
}
__device__ __forceinline__ float bf16_to_f(uint16_t h) {
  uint32_t u = ((uint32_t)h) << 16;
  return __builtin_bit_cast(float, u);
}

__device__ __forceinline__ void gl_lds16(const void* g, void* l) {
  __builtin_amdgcn_global_load_lds(
      (const __attribute__((address_space(1))) void*)g,
      (__attribute__((address_space(3))) void*)l, 16, 0, 0);
}

// ---- feature pack: fp32 [B][T][128][32][32] -> swizzled images [t][b][4cg] ----
__global__ void pack_features(const float* __restrict__ f, uint16_t* __restrict__ out) {
  const size_t i = (size_t)blockIdx.x * 256 + threadIdx.x;  // 16B-block index, < 2367488
  const int blk_s = (int)(i & 7);
  size_t pp = i >> 3;
  const int px = (int)(pp % 34); pp /= 34;
  const int yy = (int)(pp % 34); pp /= 34;
  const int cg = (int)(pp & 3);
  const int bt = (int)(pp >> 2);
  const int b = bt & 7, t = bt >> 3;
  const int blk = blk_s ^ (px & 7);
  const int pl = blk >> 2, kg = blk & 3;
  short8 sv;
  if (px == 0 || px == 33 || yy == 0 || yy == 33) {
    #pragma unroll
    for (int j = 0; j < 8; ++j) sv[j] = 0;
  } else {
    const int x = px - 1, y = yy - 1;
    #pragma unroll
    for (int j = 0; j < 8; ++j) {
      const int ch = cg * 32 + kg * 8 + j;
      const float fv = f[(((size_t)b * 8 + t) * 128 + ch) * 1024 + y * 32 + x];
      const uint16_t hi = bf16_rne(fv);
      sv[j] = (short)(pl ? bf16_rne(fv - bf16_to_f(hi)) : hi);
    }
  }
  *(short8*)(out + i * 8) = sv;
}

// ---- weight pack into swizzled images: per combo [cg][tap][nt][4096 u32] ----
struct WPackArgs {
  const float* wih[4]; const float* whh[4];
  const float* bih[4]; const float* bhh[4];
  uint32_t* wp; float* bp;
};
__global__ void pack_weights(WPackArgs A) {
  const int combo = blockIdx.y;
  const int idx = blockIdx.x * 256 + threadIdx.x;  // < 442368
  const int q = idx & 4095;
  const int rest = idx >> 12;
  const int nt = rest & 1;
  const int ct = rest >> 1;          // cg*9+tap
  const int tap = ct % 9, cg = ct / 9;
  const int w2 = q & 3;
  const int b8s = (q >> 2) & 7;
  const int hcp = (q >> 5) & 15;
  const int g = (q >> 9) & 3;
  const int pl = (q >> 11) & 1;
  const int b8 = b8s ^ (hcp & 7);
  const int kg = b8 & 3;
  const int hcl = hcp * 2 + (b8 >> 2);
  const int n = g * 64 + nt * 32 + hcl;
  const float* wih = A.wih[combo];
  const float* whh = A.whh[combo];
  uint32_t out = 0;
  #pragma unroll
  for (int e = 0; e < 2; ++e) {
    const int ch = cg * 32 + kg * 8 + w2 * 2 + e;
    const float wv = (ch < 128) ? wih[((size_t)n * 128 + ch) * 9 + tap]
                                : whh[((size_t)n * 64 + (ch - 128)) * 9 + tap];
    const uint16_t hi = bf16_rne(wv);
    const uint16_t v = pl ? bf16_rne(wv - bf16_to_f(hi)) : hi;
    out |= ((uint32_t)v) << (16 * e);
  }
  A.wp[(size_t)combo * 442368 + idx] = out;
  if (idx < 256) A.bp[combo * 256 + idx] = A.bih[combo][idx] + A.bhh[combo][idx];
}

struct StepArgs {
  const uint16_t* in0; const uint16_t* in1; const uint16_t* in2;  // images
  int nc0, nc1, nc2;         // cg counts per tensor
  const uint32_t* W;         // combo base: [cg][tap][nt][4096 u32]
  const float* bias;         // [256], n = gate*64+hc
  float* cbuf;               // plain fp32 [b][64][1024]
  uint16_t* himg;            // nullable: [b][2 cg][IMG]
  float* hf32;               // nullable: plain [b][64][1024]
};

// Block: Q4 = bx&3 (nt = Q4>>1, nq = Q4&1), band, b. NW=4 waves.
// Wave w owns MT Mtiles: mt = w*MT+m -> row mt>>1, xh mt&1; full block N=64.
// Per wave per tap: MT*2 A frags + 8 W frags, MT*12 MFMA.
template <int ROWS, int NW, int MT>
__global__ __launch_bounds__(NW * 64, 2) void conv_lstm_step(StepArgs A0, StepArgs A1) {
  static_assert(NW * MT == ROWS * 2, "wave tiling must cover the band");
  constexpr int THREADS = NW * 64;
  constexpr int BANDS = 32 / ROWS;
  constexpr int BSH = (ROWS == 4) ? 3 : 4;     // log2(BANDS)
  constexpr int ABYTES = (ROWS + 2) * ROWB;
  constexpr int ACH = (ABYTES + NW * 1024 - 1) / (NW * 1024);  // A chunks per wave
  constexpr int ASLOT = ACH * NW * 1024;
  constexpr int WCH = 8192 / (NW * 1024);      // W chunks per wave (8 KB tile): 2
  constexpr int CNT0 = WCH;                    // taps 0, >=3
  constexpr int CNT12 = WCH + ACH;             // taps 1,2

  extern __shared__ char smem[];
  char* Asm_ = smem;                           // 2 x ASLOT (A double-buffer)
  char* Wsm_ = smem + 2 * ASLOT;               // 3 x 8192 (W triple-buffer)

  const StepArgs a = (blockIdx.z == 0) ? A0 : A1;
  const int bx = blockIdx.x;
  const int Q4 = bx & 3;
  const int band = (bx >> 2) & (BANDS - 1);
  const int b = bx >> (2 + BSH);
  const int nt = Q4 >> 1;
  const int nq = Q4 & 1;
  const int y0 = band * ROWS;
  const int tid = threadIdx.x;
  const int lane = tid & 63;
  const int w = tid >> 6;
  const int m15 = lane & 15;
  const int kg = lane >> 4;

  // fragment read offsets (bytes), conflict-free via baked swizzle
  int offA[MT][3][2];   // [m][kx][pl]
  #pragma unroll
  for (int m = 0; m < MT; ++m) {
    const int mt = w * MT + m;
    const int row = mt >> 1, xh = mt & 1;
    #pragma unroll
    for (int kx = 0; kx < 3; ++kx)
      #pragma unroll
      for (int pl = 0; pl < 2; ++pl) {
        const int px = xh * 16 + kx + m15;
        const int sw = (pl * 4 + kg) ^ (px & 7);
        offA[m][kx][pl] = row * ROWB + px * 128 + sw * 16;
      }
  }
  int offW[2][4];
  {
    const int hcpl = m15 >> 1;                 // local hcp 0..7
    const int b8 = kg + 4 * (m15 & 1);
    #pragma unroll
    for (int pl = 0; pl < 2; ++pl)
      #pragma unroll
      for (int g = 0; g < 4; ++g)
        offW[pl][g] = (((pl * 4 + g) * 8 + hcpl) * 8 + (b8 ^ hcpl)) * 16;
  }

  const int ncg = a.nc0 + a.nc1 + a.nc2;
  auto abase = [&](int cg) -> const char* {
    const uint16_t* t;
    if (cg < a.nc0) t = a.in0 + ((size_t)b * a.nc0 + cg) * IMG;
    else if (cg < a.nc0 + a.nc1) t = a.in1 + ((size_t)b * a.nc1 + (cg - a.nc0)) * IMG;
    else t = a.in2 + ((size_t)b * a.nc2 + (cg - a.nc0 - a.nc1)) * IMG;
    return (const char*)t + (size_t)y0 * ROWB;
  };
  // ACH chunks/wave (ROWS+2 rows used; slot tail dead; source has PADB slack)
  auto stageA = [&](int cgi, int par) {
    const char* g = abase(cgi);
    char* d = Asm_ + par * ASLOT;
    #pragma unroll
    for (int j = 0; j < ACH; ++j)
      gl_lds16(g + (size_t)(ACH * w + j) * 1024 + lane * 16, d + (ACH * w + j) * 1024);
  };
  // nq-half of an nt W tile: 8 x 1 KB chunks, src stride 2 KB (chunk c = pl*4+g)
  auto stageW = [&](int cgs, int taps, int slot) {
    const char* g = (const char*)a.W + ((size_t)((cgs * 9 + taps) * 2 + nt) << 14)
                  + (size_t)nq * 1024;
    char* d = Wsm_ + slot * 8192;
    #pragma unroll
    for (int j = 0; j < WCH; ++j) {
      const int c = WCH * w + j;
      gl_lds16(g + (size_t)c * 2048 + lane * 16, d + c * 1024);
    }
  };

  float4v acc[MT][4];   // [m][g]
  #pragma unroll
  for (int m = 0; m < MT; ++m)
    #pragma unroll
    for (int g = 0; g < 4; ++g) acc[m][g] = (float4v){0.f, 0.f, 0.f, 0.f};

  // Prologue: A[0] then W[0,0], W[0,1] (order matters for vmcnt math).
  stageA(0, 0);
  stageW(0, 0, 0);
  stageW(0, 1, 1);

  for (int cg = 0; cg < ncg; ++cg) {
    auto tap_body = [&](auto tapc) {
      constexpr int TAP = decltype(tapc)::v;
      constexpr int CNT = (TAP == 1 || TAP == 2) ? CNT12 : CNT0;
      asm volatile("s_waitcnt vmcnt(%0)\n\ts_barrier" :: "n"(CNT) : "memory");
      const int lin = cg * 9 + TAP;
      {  // stage W for lin+2 (wrap to a dead-but-valid tile near the end)
        const int l2 = lin + 2;
        int cgs = l2 / 9;
        const int taps = l2 % 9;
        if (cgs >= ncg) cgs = 0;
        stageW(cgs, taps, l2 % 3);
      }
      if (TAP == 0) {  // stage next cg's A into the other parity
        const int nx = (cg + 1 < ncg) ? cg + 1 : 0;
        stageA(nx, (cg + 1) & 1);
      }
      constexpr int ky = TAP / 3, kx = TAP % 3;
      const char* Ab = Asm_ + (cg & 1) * ASLOT + ky * ROWB;
      const char* Wb = Wsm_ + (lin % 3) * 8192;
      short8 af[MT][2];   // [m][pl]
      #pragma unroll
      for (int m = 0; m < MT; ++m)
        #pragma unroll
        for (int pl = 0; pl < 2; ++pl)
          af[m][pl] = *(const short8*)(Ab + offA[m][kx][pl]);
      short8 wfr[2][4];
      #pragma unroll
      for (int pl = 0; pl < 2; ++pl)
        #pragma unroll
        for (int g = 0; g < 4; ++g)
          wfr[pl][g] = *(const short8*)(Wb + offW[pl][g]);
      #pragma unroll
      for (int m = 0; m < MT; ++m)
        #pragma unroll
        for (int g = 0; g < 4; ++g) {
          acc[m][g] = __builtin_amdgcn_mfma_f32_16x16x32_bf16(af[m][0], wfr[0][g], acc[m][g], 0, 0, 0);
          acc[m][g] = __builtin_amdgcn_mfma_f32_16x16x32_bf16(af[m][0], wfr[1][g], acc[m][g], 0, 0, 0);
          acc[m][g] = __builtin_amdgcn_mfma_f32_16x16x32_bf16(af[m][1], wfr[0][g], acc[m][g], 0, 0, 0);
        }
    };
    tap_body(IC<0>{}); tap_body(IC<1>{}); tap_body(IC<2>{});
    tap_body(IC<3>{}); tap_body(IC<4>{}); tap_body(IC<5>{});
    tap_body(IC<6>{}); tap_body(IC<7>{}); tap_body(IC<8>{});
  }
  asm volatile("s_waitcnt vmcnt(0)" ::: "memory");  // drain dummy restages

  // ---- fused LSTM cell epilogue ----
  const int hc = Q4 * 16 + m15;                // global hidden channel 0..63
  float bi[4];
  #pragma unroll
  for (int g = 0; g < 4; ++g) bi[g] = a.bias[g * 64 + hc];
  const int img = Q4 >> 1;                     // which 32-ch h image
  const int chi = (Q4 & 1) * 16 + m15;         // channel within image 0..31
  const int kgb = chi >> 3, jj = chi & 7;
  uint16_t* hb = a.himg ? a.himg + ((size_t)(b * 2 + img)) * IMG : nullptr;
  #pragma unroll
  for (int m = 0; m < MT; ++m) {
    const int mt = w * MT + m;
    const int y = y0 + (mt >> 1);
    const int x0 = (mt & 1) * 16 + kg * 4;
    float* crow = a.cbuf + ((size_t)(b * 64 + hc)) * 1024 + y * 32;
    float* hrow = a.hf32 ? a.hf32 + ((size_t)(b * 64 + hc)) * 1024 + y * 32 : nullptr;
    float4v cv = *(float4v*)(crow + x0);
    float4v cn, hn;
    #pragma unroll
    for (int q = 0; q < 4; ++q) {
      const float ig = 1.f / (1.f + expf(-(acc[m][0][q] + bi[0])));
      const float fg = 1.f / (1.f + expf(-(acc[m][1][q] + bi[1])));
      const float gg = tanhf(acc[m][2][q] + bi[2]);
      const float og = 1.f / (1.f + expf(-(acc[m][3][q] + bi[3])));
      const float c2 = fg * cv[q] + ig * gg;
      cn[q] = c2;
      hn[q] = og * tanhf(c2);
    }
    *(float4v*)(crow + x0) = cn;
    if (hrow) *(float4v*)(hrow + x0) = hn;
    if (hb) {
      #pragma unroll
      for (int q = 0; q < 4; ++q) {
        const int px = x0 + q + 1;
        const int sw = px & 7;
        const uint16_t hi = bf16_rne(hn[q]);
        const uint16_t lo = bf16_rne(hn[q] - bf16_to_f(hi));
        const size_t p16 = ((size_t)(y + 1) * 34 + px) * 64;
        hb[p16 + (size_t)(kgb ^ sw) * 8 + jj] = hi;
        hb[p16 + (size_t)((4 + kgb) ^ sw) * 8 + jj] = lo;
      }
    }
  }
  if (hb) {   // keep image borders zero (ws is re-poisoned every call)
    for (int i = tid; i < ROWS * 128; i += THREADS) {
      const int rr = i >> 7;
      const int hlf = (i >> 6) & 1;
      const int jx = i & 63;
      hb[((size_t)(y0 + 1 + rr) * 34 + hlf * 33) * 64 + jx] = 0;
    }
    if (band == 0) for (int i = tid; i < 2176; i += THREADS) hb[i] = 0;
    if (band == BANDS - 1) for (int i = tid; i < 2176; i += THREADS) hb[(size_t)33 * 2176 + i] = 0;
  }
}

// out[b][o][p] = relu(b_out[o] + sum_c w_out[o][c] * last[b][c][p])  (fp32 inputs)
__global__ void final_conv(const float* __restrict__ h1f_last, const float* __restrict__ h1r_last,
                           const float* __restrict__ wout, const float* __restrict__ bout,
                           float* __restrict__ out) {
  __shared__ float Ws[16 * 128];
  const int oq = blockIdx.y;
  for (int i = threadIdx.x; i < 16 * 128; i += 256) Ws[i] = wout[oq * 16 * 128 + i];
  __syncthreads();
  const int gp = blockIdx.x * 256 + threadIdx.x;
  const int b = gp >> 10, p = gp & 1023;
  float acc[16];
  #pragma unroll
  for (int o = 0; o < 16; ++o) acc[o] = bout[oq * 16 + o];
  for (int c = 0; c < 128; ++c) {
    const float xv = (c < 64) ? h1f_last[((size_t)b * 64 + c) * 1024 + p]
                              : h1r_last[((size_t)b * 64 + (c - 64)) * 1024 + p];
    #pragma unroll
    for (int o = 0; o < 16; ++o) acc[o] = fmaf(xv, Ws[o * 128 + c], acc[o]);
  }
  #pragma unroll
  for (int o = 0; o < 16; ++o) {
    const float v = acc[o];
    out[((size_t)b * 64 + oq * 16 + o) * 1024 + p] = v > 0.f ? v : 0.f;
  }
}

extern "C" void kernel_launch(void* const* d_in, const int* in_sizes, int n_in,
                              void* d_out, int out_size, void* d_ws, size_t ws_size,
                              hipStream_t stream) {
  char* p = (char*)d_ws;
  uint16_t* featImg = (uint16_t*)p; p += (size_t)8 * 8 * 4 * IMG * 2 + PADB;  // 37.9 MB
  uint32_t* WP = (uint32_t*)p;      p += (size_t)4 * 442368 * 4;              // 7.1 MB
  float* bp = (float*)p;            p += 4096;
  uint16_t* hf0i = (uint16_t*)p;    p += (size_t)9 * SLOTI * 2 + PADB;        // 21.3 MB
  uint16_t* hr0i = (uint16_t*)p;    p += (size_t)9 * SLOTI * 2 + PADB;        // 21.3 MB
  uint16_t* h1fi = (uint16_t*)p;    p += (size_t)2 * SLOTI * 2 + PADB;        // 4.7 MB
  float* c0f = (float*)p;           p += (size_t)4 * 2097152;                 // c states
  float* c0r = c0f + 524288;
  float* c1f = c0r + 524288;
  float* c1r = c1f + 524288;
  float* h1f8 = (float*)p;          p += 2097152;
  float* h1r8 = (float*)p;          p += 2097152;

  hipMemsetAsync(c0f, 0, (size_t)4 * 2097152, stream);
  hipMemsetAsync(hf0i, 0, (size_t)SLOTI * 2, stream);                     // hf0 slot 0
  hipMemsetAsync(hr0i + (size_t)8 * SLOTI, 0, (size_t)SLOTI * 2, stream); // hr0 slot 8
  hipMemsetAsync(h1fi, 0, (size_t)SLOTI * 2, stream);                     // h1f parity-0 slot

  pack_features<<<dim3(9248), 256, 0, stream>>>((const float*)d_in[0], featImg);

  WPackArgs wa;
  for (int combo = 0; combo < 4; ++combo) {
    const int base = 1 + combo * 4;
    wa.wih[combo] = (const float*)d_in[base];
    wa.whh[combo] = (const float*)d_in[base + 1];
    wa.bih[combo] = (const float*)d_in[base + 2];
    wa.bhh[combo] = (const float*)d_in[base + 3];
  }
  wa.wp = WP; wa.bp = bp;
  pack_weights<<<dim3(1728, 4), 256, 0, stream>>>(wa);

  // Paired <4,4,2>: ASLOT = 7*4*1024 = 28672; LDS = 2*28672 + 3*8192 = 81920.
  //   2 blocks/CU = 163840 = full 160 KiB.
  // Solo   <2,4,1>: ASLOT = 5*4*1024 = 20480; LDS = 2*20480 + 3*8192 = 65536.
  constexpr int DYN_P = 2 * 28672 + 3 * 8192;
  constexpr int DYN_S = 2 * 20480 + 3 * 8192;
  (void)hipFuncSetAttribute((const void*)(conv_lstm_step<4, 4, 2>),
                            hipFuncAttributeMaxDynamicSharedMemorySize, DYN_P);
  (void)hipFuncSetAttribute((const void*)(conv_lstm_step<2, 4, 1>),
                            hipFuncAttributeMaxDynamicSharedMemorySize, DYN_S);

  auto mk = [&](const uint16_t* i0, int n0, const uint16_t* i1, int n1,
                const uint16_t* i2, int n2, int combo, float* cb,
                uint16_t* himg, float* hf32) {
    StepArgs s;
    s.in0 = i0; s.in1 = i1; s.in2 = i2;
    s.nc0 = n0; s.nc1 = n1; s.nc2 = n2;
    s.W = WP + (size_t)combo * 442368; s.bias = bp + combo * 256;
    s.cbuf = cb; s.himg = himg; s.hf32 = hf32;
    return s;
  };

  // Layer 0: 8 pair launches (fwd step k, rev step 7-k); 256 blocks/dir x z=2.
  for (int k = 0; k < 8; ++k) {
    const int tr = 7 - k;
    StepArgs f = mk(featImg + (size_t)k * 8 * 4 * IMG, 4,
                    hf0i + (size_t)k * SLOTI, 2, nullptr, 0,
                    0, c0f, hf0i + (size_t)(k + 1) * SLOTI, nullptr);
    StepArgs r = mk(featImg + (size_t)tr * 8 * 4 * IMG, 4,
                    hr0i + (size_t)(tr + 1) * SLOTI, 2, nullptr, 0,
                    1, c0r, hr0i + (size_t)tr * SLOTI, nullptr);
    conv_lstm_step<4, 4, 2><<<dim3(256, 1, 2), 256, DYN_P, stream>>>(f, r);
  }

  // Layer 1: fwd t=0 pairs with the single reverse step (t=7, zero init state).
  // Solo steps t=1..7: <2,4,1> at 512 blocks (2 blocks/CU), 256 thr.
  for (int t = 0; t < 8; ++t) {
    uint16_t* himg = (t < 7) ? h1fi + (size_t)((t + 1) & 1) * SLOTI : nullptr;
    float* hf32 = (t == 7) ? h1f8 : nullptr;
    StepArgs s = mk(hf0i + (size_t)(t + 1) * SLOTI, 2, hr0i + (size_t)t * SLOTI, 2,
                    h1fi + (size_t)(t & 1) * SLOTI, 2, 2, c1f, himg, hf32);
    if (t == 0) {
      StepArgs rv = mk(hf0i + (size_t)8 * SLOTI, 2, hr0i + (size_t)7 * SLOTI, 2,
                       nullptr, 0, 3, c1r, nullptr, h1r8);
      conv_lstm_step<4, 4, 2><<<dim3(256, 1, 2), 256, DYN_P, stream>>>(s, rv);
    } else {
      conv_lstm_step<2, 4, 1><<<dim3(512, 1, 1), 256, DYN_S, stream>>>(s, s);
    }
  }

  final_conv<<<dim3(32, 4), 256, 0, stream>>>(
      h1f8, h1r8, (const float*)d_in[17], (const float*)d_in[18], (float*)d_out);
}

// Round 6
// 708.429 us; speedup vs baseline: 1.1457x; 1.0485x over previous
//
#include <hip/hip_runtime.h>
#include <math.h>
#include <stdint.h>

// ConvLSTM (Seq2VecRNN2D) round 11: best-known R3 structure (725us) + micro-package:
//   (1) compile-time tap arithmetic: staged W slot (TAP+2)%3, read slot TAP%3
//       (9 ≡ 0 mod 3), no runtime /9 %9 %3 chains in the hot loop;
//   (2) running wave-uniform W source pointer (+32768/tap, SALU) instead of the
//       per-tap ((cg*9+tap)*2+nt)<<14 64-bit VALU chain;
//   (3) s_setprio(1/0) around the MFMA cluster (isolated T5 probe).
// Schedule, layout, grid, vmcnt counts bit-identical to R3.
//   Paired <ROWS=4>: 512 thr, 128 blocks x z=2 (R0-proven 42.5us schedule).
//   Solo   <ROWS=2>: 256 thr, 256 blocks (full GPU), layer-1 t=1..7.
// B=8 T=8 CIN=128 HID=64 G=256 H=W=32.
//
// Activation image per (slot,b,cg32): [34 y'][34 px][8 blk of 16B], blk = pl*4+kg
// stored at blk^(px&7); ch = cg*32+kg*8+j, pl0=hi bf16, pl1=lo bf16. Borders zero.
// Weight image per (combo,cg,tap,nt): [pl][4 g][16 hcp][8 b8 of 16B], b8 = kg+4*(hc&1)
// stored at b8^(hcp&7); hcp = hc_local>>1.
//
// DMA schedule (per wave, per barrier interval): WCH W chunks always; +ACH A chunks
// at tap==0. vmcnt before barrier of tap t (in-order retirement, queue-simulated):
//   ROWS=4 (ACH=4,WCH=2): tap0: 2, tap1: 6, tap2: 6, tap>=3: 2   (round-0 exact)
//   ROWS=2 (ACH=5,WCH=4): tap0: 4, tap1: 9, tap2: 9, tap>=3: 4

typedef __attribute__((ext_vector_type(8))) short short8;
typedef __attribute__((ext_vector_type(4))) float float4v;

namespace {
constexpr int IMG = 34 * 34 * 64;            // u16 per (slot,b,cg) image
constexpr size_t SLOTI = 16ull * IMG;        // u16 per h slot (8 b x 2 cg)
constexpr int ROWB = 34 * 128;               // bytes per image row (4352)
constexpr int PADB = 8192;                   // tail slack for DMA overshoot
}
template <int N> struct IC { static constexpr int v = N; };

__device__ __forceinline__ uint16_t bf16_rne(float x) {
  uint32_t u = __builtin_bit_cast(uint32_t, x);
  return (uint16_t)((u + 0x7FFFu + ((u >> 16) & 1u)) >> 16);
}
__device__ __forceinline__ float bf16_to_f(uint16_t h) {
  uint32_t u = ((uint32_t)h) << 16;
  return __builtin_bit_cast(float, u);
}

__device__ __forceinline__ void gl_lds16(const void* g, void* l) {
  __builtin_amdgcn_global_load_lds(
      (const __attribute__((address_space(1))) void*)g,
      (__attribute__((address_space(3))) void*)l, 16, 0, 0);
}

// ---- feature pack: fp32 [B][T][128][32][32] -> swizzled images [t][b][4cg] ----
__global__ void pack_features(const float* __restrict__ f, uint16_t* __restrict__ out) {
  const size_t i = (size_t)blockIdx.x * 256 + threadIdx.x;  // 16B-block index, < 2367488
  const int blk_s = (int)(i & 7);
  size_t pp = i >> 3;
  const int px = (int)(pp % 34); pp /= 34;
  const int yy = (int)(pp % 34); pp /= 34;
  const int cg = (int)(pp & 3);
  const int bt = (int)(pp >> 2);
  const int b = bt & 7, t = bt >> 3;
  const int blk = blk_s ^ (px & 7);
  const int pl = blk >> 2, kg = blk & 3;
  short8 sv;
  if (px == 0 || px == 33 || yy == 0 || yy == 33) {
    #pragma unroll
    for (int j = 0; j < 8; ++j) sv[j] = 0;
  } else {
    const int x = px - 1, y = yy - 1;
    #pragma unroll
    for (int j = 0; j < 8; ++j) {
      const int ch = cg * 32 + kg * 8 + j;
      const float fv = f[(((size_t)b * 8 + t) * 128 + ch) * 1024 + y * 32 + x];
      const uint16_t hi = bf16_rne(fv);
      sv[j] = (short)(pl ? bf16_rne(fv - bf16_to_f(hi)) : hi);
    }
  }
  *(short8*)(out + i * 8) = sv;
}

// ---- weight pack into swizzled images: per combo [cg][tap][nt][4096 u32] ----
struct WPackArgs {
  const float* wih[4]; const float* whh[4];
  const float* bih[4]; const float* bhh[4];
  uint32_t* wp; float* bp;
};
__global__ void pack_weights(WPackArgs A) {
  const int combo = blockIdx.y;
  const int idx = blockIdx.x * 256 + threadIdx.x;  // < 442368
  const int q = idx & 4095;
  const int rest = idx >> 12;
  const int nt = rest & 1;
  const int ct = rest >> 1;          // cg*9+tap
  const int tap = ct % 9, cg = ct / 9;
  const int w2 = q & 3;
  const int b8s = (q >> 2) & 7;
  const int hcp = (q >> 5) & 15;
  const int g = (q >> 9) & 3;
  const int pl = (q >> 11) & 1;
  const int b8 = b8s ^ (hcp & 7);
  const int kg = b8 & 3;
  const int hcl = hcp * 2 + (b8 >> 2);
  const int n = g * 64 + nt * 32 + hcl;
  const float* wih = A.wih[combo];
  const float* whh = A.whh[combo];
  uint32_t out = 0;
  #pragma unroll
  for (int e = 0; e < 2; ++e) {
    const int ch = cg * 32 + kg * 8 + w2 * 2 + e;
    const float wv = (ch < 128) ? wih[((size_t)n * 128 + ch) * 9 + tap]
                                : whh[((size_t)n * 64 + (ch - 128)) * 9 + tap];
    const uint16_t hi = bf16_rne(wv);
    const uint16_t v = pl ? bf16_rne(wv - bf16_to_f(hi)) : hi;
    out |= ((uint32_t)v) << (16 * e);
  }
  A.wp[(size_t)combo * 442368 + idx] = out;
  if (idx < 256) A.bp[combo * 256 + idx] = A.bih[combo][idx] + A.bhh[combo][idx];
}

struct StepArgs {
  const uint16_t* in0; const uint16_t* in1; const uint16_t* in2;  // images
  int nc0, nc1, nc2;         // cg counts per tensor
  const uint32_t* W;         // combo base: [cg][tap][nt][4096 u32]
  const float* bias;         // [256], n = gate*64+hc
  float* cbuf;               // plain fp32 [b][64][1024]
  uint16_t* himg;            // nullable: [b][2 cg][IMG]
  float* hf32;               // nullable: plain [b][64][1024]
};

// ROWS=4: 512 thr, grid bx = b(8) x band(8) x nt(2);  wave: r=w&3, hcg=w>>2.
// ROWS=2: 256 thr, grid bx = b(8) x band(16) x nt(2); wave: r=w&1, hcg=w>>1.
// Per wave: 2 x-halves x 4 gates (tile 32x64).
template <int ROWS>
__global__ __launch_bounds__(ROWS * 128, ROWS / 2) void conv_lstm_step(StepArgs A0, StepArgs A1) {
  constexpr int NW = ROWS * 2;                 // waves per block
  constexpr int THREADS = NW * 64;
  constexpr int BANDS = 32 / ROWS;
  constexpr int LOGB = (ROWS == 4) ? 3 : 4;
  constexpr int ACH = (ROWS == 4) ? 4 : 5;     // A chunks per wave
  constexpr int ASLOT = ACH * NW * 1024;       // 32768 / 20480
  constexpr int WCH = 16384 / (NW * 1024);     // W chunks per wave: 2 / 4
  constexpr int CNT0 = WCH;                    // taps 0, >=3
  constexpr int CNT12 = WCH + ACH;             // taps 1,2:  6 / 9

  extern __shared__ char smem[];
  char* Asm_ = smem;                           // 2 x ASLOT (A double-buffer)
  char* Wsm_ = smem + 2 * ASLOT;               // 3 x 16384 (W triple-buffer)

  const StepArgs a = (blockIdx.z == 0) ? A0 : A1;
  const int bx = blockIdx.x;
  const int nt = bx & 1;
  const int band = (bx >> 1) & (BANDS - 1);
  const int b = bx >> (1 + LOGB);
  const int y0 = band * ROWS;
  const int tid = threadIdx.x;
  const int lane = tid & 63;
  const int w = tid >> 6;
  const int m15 = lane & 15;
  const int kg = lane >> 4;
  const int r = w & (ROWS - 1);
  const int hcg = (ROWS == 4) ? (w >> 2) : (w >> 1);

  // fragment read offsets (bytes), conflict-free via baked swizzle
  int offA[2][3][2];
  #pragma unroll
  for (int xh = 0; xh < 2; ++xh)
    #pragma unroll
    for (int kx = 0; kx < 3; ++kx)
      #pragma unroll
      for (int pl = 0; pl < 2; ++pl) {
        const int px = xh * 16 + kx + m15;
        const int sw = (pl * 4 + kg) ^ (px & 7);
        offA[xh][kx][pl] = r * ROWB + px * 128 + sw * 16;
      }
  int offW[2][4];
  {
    const int hcp = hcg * 8 + (m15 >> 1);
    const int b8 = kg + 4 * (m15 & 1);
    #pragma unroll
    for (int pl = 0; pl < 2; ++pl)
      #pragma unroll
      for (int g = 0; g < 4; ++g)
        offW[pl][g] = (((pl * 4 + g) * 16 + hcp) * 8 + (b8 ^ (hcp & 7))) * 16;
  }

  const int ncg = a.nc0 + a.nc1 + a.nc2;
  auto abase = [&](int cg) -> const char* {
    const uint16_t* t;
    if (cg < a.nc0) t = a.in0 + ((size_t)b * a.nc0 + cg) * IMG;
    else if (cg < a.nc0 + a.nc1) t = a.in1 + ((size_t)b * a.nc1 + (cg - a.nc0)) * IMG;
    else t = a.in2 + ((size_t)b * a.nc2 + (cg - a.nc0 - a.nc1)) * IMG;
    return (const char*)t + (size_t)y0 * ROWB;
  };
  // ACH chunks/wave (ROWS+2 rows used, tail lands in dead LDS; source has PADB slack)
  auto stageA = [&](int cgi, int par) {
    const char* g = abase(cgi);
    char* d = Asm_ + par * ASLOT;
    #pragma unroll
    for (int j = 0; j < ACH; ++j)
      gl_lds16(g + (size_t)(ACH * w + j) * 1024 + lane * 16, d + (ACH * w + j) * 1024);
  };
  // W: running wave-uniform source pointer (SALU increment), WCH chunks per 16 KB tile.
  const char* const wbeg = (const char*)a.W + (size_t)nt * 16384;
  const char* const wend = (const char*)a.W + (size_t)ncg * 9 * 32768;
  const char* wsrc = wbeg;
  auto stageW = [&](int slot) {
    char* d = Wsm_ + slot * 16384;
    #pragma unroll
    for (int j = 0; j < WCH; ++j)
      gl_lds16(wsrc + (size_t)(WCH * w + j) * 1024 + lane * 16, d + (WCH * w + j) * 1024);
    wsrc += 32768;
    if (wsrc >= wend) wsrc = wbeg;   // dummy restage near the tail (valid memory)
  };

  float4v acc[2][4];
  #pragma unroll
  for (int xh = 0; xh < 2; ++xh)
    #pragma unroll
    for (int g = 0; g < 4; ++g) acc[xh][g] = (float4v){0.f, 0.f, 0.f, 0.f};

  // Prologue: A[0] then W[0] -> slot0, W[1] -> slot1 (order matters for vmcnt math).
  stageA(0, 0);
  stageW(0);
  stageW(1);

  for (int cg = 0; cg < ncg; ++cg) {
    auto tap_body = [&](auto tapc) {
      constexpr int TAP = decltype(tapc)::v;
      constexpr int CNT = (TAP == 1 || TAP == 2) ? CNT12 : CNT0;
      constexpr int SLOT2 = (TAP + 2) % 3;   // slot of the tile staged now (lin+2)
      constexpr int SLOTR = TAP % 3;         // slot read this tap (lin%3 == TAP%3)
      asm volatile("s_waitcnt vmcnt(%0)\n\ts_barrier" :: "n"(CNT) : "memory");
      stageW(SLOT2);                         // wsrc tracks lin+2 linearly
      if (TAP == 0) {  // stage next cg's A into the other parity
        const int nx = (cg + 1 < ncg) ? cg + 1 : 0;
        stageA(nx, (cg + 1) & 1);
      }
      constexpr int ky = TAP / 3, kx = TAP % 3;
      const char* Ab = Asm_ + (cg & 1) * ASLOT + ky * ROWB;
      const char* Wb = Wsm_ + SLOTR * 16384;
      short8 af[2][2];
      #pragma unroll
      for (int xh = 0; xh < 2; ++xh)
        #pragma unroll
        for (int pl = 0; pl < 2; ++pl)
          af[xh][pl] = *(const short8*)(Ab + offA[xh][kx][pl]);
      short8 wfr[2][4];
      #pragma unroll
      for (int pl = 0; pl < 2; ++pl)
        #pragma unroll
        for (int g = 0; g < 4; ++g)
          wfr[pl][g] = *(const short8*)(Wb + offW[pl][g]);
      __builtin_amdgcn_s_setprio(1);
      #pragma unroll
      for (int xh = 0; xh < 2; ++xh)
        #pragma unroll
        for (int g = 0; g < 4; ++g) {
          acc[xh][g] = __builtin_amdgcn_mfma_f32_16x16x32_bf16(af[xh][0], wfr[0][g], acc[xh][g], 0, 0, 0);
          acc[xh][g] = __builtin_amdgcn_mfma_f32_16x16x32_bf16(af[xh][0], wfr[1][g], acc[xh][g], 0, 0, 0);
          acc[xh][g] = __builtin_amdgcn_mfma_f32_16x16x32_bf16(af[xh][1], wfr[0][g], acc[xh][g], 0, 0, 0);
        }
      __builtin_amdgcn_s_setprio(0);
    };
    tap_body(IC<0>{}); tap_body(IC<1>{}); tap_body(IC<2>{});
    tap_body(IC<3>{}); tap_body(IC<4>{}); tap_body(IC<5>{});
    tap_body(IC<6>{}); tap_body(IC<7>{}); tap_body(IC<8>{});
  }
  asm volatile("s_waitcnt vmcnt(0)" ::: "memory");  // drain dummy restages

  // ---- fused LSTM cell epilogue ----
  const int hcl = hcg * 16 + m15;
  const int hc = nt * 32 + hcl;
  const int y = y0 + r;
  float bi[4];
  #pragma unroll
  for (int g = 0; g < 4; ++g) bi[g] = a.bias[g * 64 + hc];
  float* crow = a.cbuf + ((size_t)(b * 64 + hc)) * 1024 + y * 32;
  float* hrow = a.hf32 ? a.hf32 + ((size_t)(b * 64 + hc)) * 1024 + y * 32 : nullptr;
  uint16_t* hb = a.himg ? a.himg + ((size_t)(b * 2 + nt)) * IMG : nullptr;
  const int kgb = hcl >> 3, jj = hcl & 7;
  #pragma unroll
  for (int xh = 0; xh < 2; ++xh) {
    const int x0 = xh * 16 + kg * 4;
    float4v cv = *(float4v*)(crow + x0);
    float4v cn, hn;
    #pragma unroll
    for (int q = 0; q < 4; ++q) {
      const float ig = 1.f / (1.f + expf(-(acc[xh][0][q] + bi[0])));
      const float fg = 1.f / (1.f + expf(-(acc[xh][1][q] + bi[1])));
      const float gg = tanhf(acc[xh][2][q] + bi[2]);
      const float og = 1.f / (1.f + expf(-(acc[xh][3][q] + bi[3])));
      const float c2 = fg * cv[q] + ig * gg;
      cn[q] = c2;
      hn[q] = og * tanhf(c2);
    }
    *(float4v*)(crow + x0) = cn;
    if (hrow) *(float4v*)(hrow + x0) = hn;
    if (hb) {
      #pragma unroll
      for (int q = 0; q < 4; ++q) {
        const int px = x0 + q + 1;
        const int sw = px & 7;
        const uint16_t hi = bf16_rne(hn[q]);
        const uint16_t lo = bf16_rne(hn[q] - bf16_to_f(hi));
        const size_t p16 = ((size_t)(y + 1) * 34 + px) * 64;
        hb[p16 + (size_t)(kgb ^ sw) * 8 + jj] = hi;
        hb[p16 + (size_t)((4 + kgb) ^ sw) * 8 + jj] = lo;
      }
    }
  }
  if (hb) {   // keep image borders zero (ws is re-poisoned every call)
    {
      const int rr = tid >> 7;             // 0..ROWS-1 (THREADS = ROWS*128)
      const int hlf = (tid >> 6) & 1;
      const int jx = tid & 63;
      hb[((size_t)(y0 + 1 + rr) * 34 + hlf * 33) * 64 + jx] = 0;
    }
    if (band == 0) for (int i = tid; i < 2176; i += THREADS) hb[i] = 0;
    if (band == BANDS - 1) for (int i = tid; i < 2176; i += THREADS) hb[(size_t)33 * 2176 + i] = 0;
  }
}

// out[b][o][p] = relu(b_out[o] + sum_c w_out[o][c] * last[b][c][p])  (fp32 inputs)
__global__ void final_conv(const float* __restrict__ h1f_last, const float* __restrict__ h1r_last,
                           const float* __restrict__ wout, const float* __restrict__ bout,
                           float* __restrict__ out) {
  __shared__ float Ws[16 * 128];
  const int oq = blockIdx.y;
  for (int i = threadIdx.x; i < 16 * 128; i += 256) Ws[i] = wout[oq * 16 * 128 + i];
  __syncthreads();
  const int gp = blockIdx.x * 256 + threadIdx.x;
  const int b = gp >> 10, p = gp & 1023;
  float acc[16];
  #pragma unroll
  for (int o = 0; o < 16; ++o) acc[o] = bout[oq * 16 + o];
  for (int c = 0; c < 128; ++c) {
    const float xv = (c < 64) ? h1f_last[((size_t)b * 64 + c) * 1024 + p]
                              : h1r_last[((size_t)b * 64 + (c - 64)) * 1024 + p];
    #pragma unroll
    for (int o = 0; o < 16; ++o) acc[o] = fmaf(xv, Ws[o * 128 + c], acc[o]);
  }
  #pragma unroll
  for (int o = 0; o < 16; ++o) {
    const float v = acc[o];
    out[((size_t)b * 64 + oq * 16 + o) * 1024 + p] = v > 0.f ? v : 0.f;
  }
}

extern "C" void kernel_launch(void* const* d_in, const int* in_sizes, int n_in,
                              void* d_out, int out_size, void* d_ws, size_t ws_size,
                              hipStream_t stream) {
  char* p = (char*)d_ws;
  uint16_t* featImg = (uint16_t*)p; p += (size_t)8 * 8 * 4 * IMG * 2 + PADB;  // 37.9 MB
  uint32_t* WP = (uint32_t*)p;      p += (size_t)4 * 442368 * 4;              // 7.1 MB
  float* bp = (float*)p;            p += 4096;
  uint16_t* hf0i = (uint16_t*)p;    p += (size_t)9 * SLOTI * 2 + PADB;        // 21.3 MB
  uint16_t* hr0i = (uint16_t*)p;    p += (size_t)9 * SLOTI * 2 + PADB;        // 21.3 MB
  uint16_t* h1fi = (uint16_t*)p;    p += (size_t)2 * SLOTI * 2 + PADB;        // 4.7 MB
  float* c0f = (float*)p;           p += (size_t)4 * 2097152;                 // c states
  float* c0r = c0f + 524288;
  float* c1f = c0r + 524288;
  float* c1r = c1f + 524288;
  float* h1f8 = (float*)p;          p += 2097152;
  float* h1r8 = (float*)p;          p += 2097152;

  hipMemsetAsync(c0f, 0, (size_t)4 * 2097152, stream);
  hipMemsetAsync(hf0i, 0, (size_t)SLOTI * 2, stream);                     // hf0 slot 0
  hipMemsetAsync(hr0i + (size_t)8 * SLOTI, 0, (size_t)SLOTI * 2, stream); // hr0 slot 8
  hipMemsetAsync(h1fi, 0, (size_t)SLOTI * 2, stream);                     // h1f parity-0 slot

  pack_features<<<dim3(9248), 256, 0, stream>>>((const float*)d_in[0], featImg);

  WPackArgs wa;
  for (int combo = 0; combo < 4; ++combo) {
    const int base = 1 + combo * 4;
    wa.wih[combo] = (const float*)d_in[base];
    wa.whh[combo] = (const float*)d_in[base + 1];
    wa.bih[combo] = (const float*)d_in[base + 2];
    wa.bhh[combo] = (const float*)d_in[base + 3];
  }
  wa.wp = WP; wa.bp = bp;
  pack_weights<<<dim3(1728, 4), 256, 0, stream>>>(wa);

  constexpr int DYN4 = 2 * 32768 + 3 * 16384;   // 114688: ROWS=4
  constexpr int DYN2 = 2 * 20480 + 3 * 16384;   // 90112:  ROWS=2
  (void)hipFuncSetAttribute((const void*)(conv_lstm_step<4>),
                            hipFuncAttributeMaxDynamicSharedMemorySize, DYN4);
  (void)hipFuncSetAttribute((const void*)(conv_lstm_step<2>),
                            hipFuncAttributeMaxDynamicSharedMemorySize, DYN2);

  auto mk = [&](const uint16_t* i0, int n0, const uint16_t* i1, int n1,
                const uint16_t* i2, int n2, int combo, float* cb,
                uint16_t* himg, float* hf32) {
    StepArgs s;
    s.in0 = i0; s.in1 = i1; s.in2 = i2;
    s.nc0 = n0; s.nc1 = n1; s.nc2 = n2;
    s.W = WP + (size_t)combo * 442368; s.bias = bp + combo * 256;
    s.cbuf = cb; s.himg = himg; s.hf32 = hf32;
    return s;
  };

  // Layer 0: 8 pair launches (fwd step k, rev step 7-k); 128 blocks/dir, 512 thr.
  for (int k = 0; k < 8; ++k) {
    const int tr = 7 - k;
    StepArgs f = mk(featImg + (size_t)k * 8 * 4 * IMG, 4,
                    hf0i + (size_t)k * SLOTI, 2, nullptr, 0,
                    0, c0f, hf0i + (size_t)(k + 1) * SLOTI, nullptr);
    StepArgs r = mk(featImg + (size_t)tr * 8 * 4 * IMG, 4,
                    hr0i + (size_t)(tr + 1) * SLOTI, 2, nullptr, 0,
                    1, c0r, hr0i + (size_t)tr * SLOTI, nullptr);
    conv_lstm_step<4><<<dim3(128, 1, 2), 512, DYN4, stream>>>(f, r);
  }

  // Layer 1: fwd t=0 pairs with the single reverse step (t=7, zero init state).
  // Solo steps t=1..7 use the ROWS=2 kernel: 256 blocks (full GPU), 256 thr.
  for (int t = 0; t < 8; ++t) {
    uint16_t* himg = (t < 7) ? h1fi + (size_t)((t + 1) & 1) * SLOTI : nullptr;
    float* hf32 = (t == 7) ? h1f8 : nullptr;
    StepArgs s = mk(hf0i + (size_t)(t + 1) * SLOTI, 2, hr0i + (size_t)t * SLOTI, 2,
                    h1fi + (size_t)(t & 1) * SLOTI, 2, 2, c1f, himg, hf32);
    if (t == 0) {
      StepArgs rv = mk(hf0i + (size_t)8 * SLOTI, 2, hr0i + (size_t)7 * SLOTI, 2,
                       nullptr, 0, 3, c1r, nullptr, h1r8);
      conv_lstm_step<4><<<dim3(128, 1, 2), 512, DYN4, stream>>>(s, rv);
    } else {
      conv_lstm_step<2><<<dim3(256, 1, 1), 256, DYN2, stream>>>(s, s);
    }
  }

  final_conv<<<dim3(32, 4), 256, 0, stream>>>(
      h1f8, h1r8, (const float*)d_in[17], (const float*)d_in[18], (float*)d_out);
}

// Round 8
// 697.643 us; speedup vs baseline: 1.1634x; 1.0155x over previous
//
#include <hip/hip_runtime.h>
#include <math.h>
#include <stdint.h>

// ConvLSTM (Seq2VecRNN2D) round 13: R7 structure with the W-base fix. Layer-1 input
// projections (W_ih1 * xs1) precomputed in ONE batched dispatch (conv_gates_pre ->
// fp32 gpre[9 slots]); the 7 serial layer-1 solo steps are ncg=2 (h-recurrence only,
// W base offset to cg4 = W_hh taps  <-- R7 bug: base was cg0 = W_ih) and add gpre
// in the epilogue. Zero-h steps (L1 fwd t=0, L1 rev) are ncg=0 pure LSTM-cell
// launches; L0 round 0 drops its zero-h cgs (ncg=4).
// B=8 T=8 CIN=128 HID=64 G=256 H=W=32.
//
// Activation image per (slot,b,cg32): [34 y'][34 px][8 blk of 16B], blk = pl*4+kg
// stored at blk^(px&7); ch = cg*32+kg*8+j, pl0=hi bf16, pl1=lo bf16. Borders zero.
// Weight image per (combo,cg,tap,nt): [pl][4 g][16 hcp][8 b8 of 16B], b8 = kg+4*(hc&1)
// stored at b8^(hcp&7); hcp = hc_local>>1. 73728 u32 per cg (9 tap x 2 nt x 4096).
//
// DMA schedule (per wave, per barrier interval): WCH W chunks always; +ACH A chunks
// at tap==0. vmcnt before barrier of tap t (in-order retirement, queue-simulated):
//   ROWS=4 (ACH=4,WCH=2): tap0: 2, tap1: 6, tap2: 6, tap>=3: 2   (round-0 exact)
//   ROWS=2 (ACH=5,WCH=4): tap0: 4, tap1: 9, tap2: 9, tap>=3: 4

typedef __attribute__((ext_vector_type(8))) short short8;
typedef __attribute__((ext_vector_type(4))) float float4v;

namespace {
constexpr int IMG = 34 * 34 * 64;            // u16 per (slot,b,cg) image
constexpr size_t SLOTI = 16ull * IMG;        // u16 per h slot (8 b x 2 cg)
constexpr int ROWB = 34 * 128;               // bytes per image row (4352)
constexpr int PADB = 8192;                   // tail slack for DMA overshoot
constexpr size_t GSLOT = 8ull * 256 * 1024;  // fp32 per gpre slot (8 b)
constexpr int CGU32 = 73728;                 // u32 per cg in the weight image
}
template <int N> struct IC { static constexpr int v = N; };

__device__ __forceinline__ uint16_t bf16_rne(float x) {
  uint32_t u = __builtin_bit_cast(uint32_t, x);
  return (uint16_t)((u + 0x7FFFu + ((u >> 16) & 1u)) >> 16);
}
__device__ __forceinline__ float bf16_to_f(uint16_t h) {
  uint32_t u = ((uint32_t)h) << 16;
  return __builtin_bit_cast(float, u);
}

__device__ __forceinline__ void gl_lds16(const void* g, void* l) {
  __builtin_amdgcn_global_load_lds(
      (const __attribute__((address_space(1))) void*)g,
      (__attribute__((address_space(3))) void*)l, 16, 0, 0);
}

// ---- feature pack: fp32 [B][T][128][32][32] -> swizzled images [t][b][4cg] ----
__global__ void pack_features(const float* __restrict__ f, uint16_t* __restrict__ out) {
  const size_t i = (size_t)blockIdx.x * 256 + threadIdx.x;  // 16B-block index, < 2367488
  const int blk_s = (int)(i & 7);
  size_t pp = i >> 3;
  const int px = (int)(pp % 34); pp /= 34;
  const int yy = (int)(pp % 34); pp /= 34;
  const int cg = (int)(pp & 3);
  const int bt = (int)(pp >> 2);
  const int b = bt & 7, t = bt >> 3;
  const int blk = blk_s ^ (px & 7);
  const int pl = blk >> 2, kg = blk & 3;
  short8 sv;
  if (px == 0 || px == 33 || yy == 0 || yy == 33) {
    #pragma unroll
    for (int j = 0; j < 8; ++j) sv[j] = 0;
  } else {
    const int x = px - 1, y = yy - 1;
    #pragma unroll
    for (int j = 0; j < 8; ++j) {
      const int ch = cg * 32 + kg * 8 + j;
      const float fv = f[(((size_t)b * 8 + t) * 128 + ch) * 1024 + y * 32 + x];
      const uint16_t hi = bf16_rne(fv);
      sv[j] = (short)(pl ? bf16_rne(fv - bf16_to_f(hi)) : hi);
    }
  }
  *(short8*)(out + i * 8) = sv;
}

// ---- weight pack into swizzled images: per combo [cg][tap][nt][4096 u32] ----
struct WPackArgs {
  const float* wih[4]; const float* whh[4];
  const float* bih[4]; const float* bhh[4];
  uint32_t* wp; float* bp;
};
__global__ void pack_weights(WPackArgs A) {
  const int combo = blockIdx.y;
  const int idx = blockIdx.x * 256 + threadIdx.x;  // < 442368
  const int q = idx & 4095;
  const int rest = idx >> 12;
  const int nt = rest & 1;
  const int ct = rest >> 1;          // cg*9+tap
  const int tap = ct % 9, cg = ct / 9;
  const int w2 = q & 3;
  const int b8s = (q >> 2) & 7;
  const int hcp = (q >> 5) & 15;
  const int g = (q >> 9) & 3;
  const int pl = (q >> 11) & 1;
  const int b8 = b8s ^ (hcp & 7);
  const int kg = b8 & 3;
  const int hcl = hcp * 2 + (b8 >> 2);
  const int n = g * 64 + nt * 32 + hcl;
  const float* wih = A.wih[combo];
  const float* whh = A.whh[combo];
  uint32_t out = 0;
  #pragma unroll
  for (int e = 0; e < 2; ++e) {
    const int ch = cg * 32 + kg * 8 + w2 * 2 + e;
    const float wv = (ch < 128) ? wih[((size_t)n * 128 + ch) * 9 + tap]
                                : whh[((size_t)n * 64 + (ch - 128)) * 9 + tap];
    const uint16_t hi = bf16_rne(wv);
    const uint16_t v = pl ? bf16_rne(wv - bf16_to_f(hi)) : hi;
    out |= ((uint32_t)v) << (16 * e);
  }
  A.wp[(size_t)combo * 442368 + idx] = out;
  if (idx < 256) A.bp[combo * 256 + idx] = A.bih[combo][idx] + A.bhh[combo][idx];
}

struct StepArgs {
  const uint16_t* in0; const uint16_t* in1; const uint16_t* in2;  // images
  int nc0, nc1, nc2;         // cg counts per tensor
  const uint32_t* W;         // weight base for cg 0 of THIS step's conv
  const float* bias;         // [256], n = gate*64+hc (used when gpre==null)
  const float* gpre;         // nullable: precomputed gate preact [b][256][1024]
  float* cbuf;               // plain fp32 [b][64][1024]
  uint16_t* himg;            // nullable: [b][2 cg][IMG]
  float* hf32;               // nullable: plain [b][64][1024]
};

// ROWS=4: 512 thr, grid bx = b(8) x band(8) x nt(2);  wave: r=w&3, hcg=w>>2.
// ROWS=2: 256 thr, grid bx = b(8) x band(16) x nt(2); wave: r=w&1, hcg=w>>1.
// Per wave: 2 x-halves x 4 gates (tile 32x64).  ncg==0: pure LSTM-cell on gpre.
template <int ROWS>
__global__ __launch_bounds__(ROWS * 128, ROWS / 2) void conv_lstm_step(StepArgs A0, StepArgs A1) {
  constexpr int NW = ROWS * 2;                 // waves per block
  constexpr int THREADS = NW * 64;
  constexpr int BANDS = 32 / ROWS;
  constexpr int LOGB = (ROWS == 4) ? 3 : 4;
  constexpr int ACH = (ROWS == 4) ? 4 : 5;     // A chunks per wave
  constexpr int ASLOT = ACH * NW * 1024;       // 32768 / 20480
  constexpr int WCH = 16384 / (NW * 1024);     // W chunks per wave: 2 / 4
  constexpr int CNT0 = WCH;                    // taps 0, >=3
  constexpr int CNT12 = WCH + ACH;             // taps 1,2:  6 / 9

  extern __shared__ char smem[];
  char* Asm_ = smem;                           // 2 x ASLOT (A double-buffer)
  char* Wsm_ = smem + 2 * ASLOT;               // 3 x 16384 (W triple-buffer)

  const StepArgs a = (blockIdx.z == 0) ? A0 : A1;
  const int bx = blockIdx.x;
  const int nt = bx & 1;
  const int band = (bx >> 1) & (BANDS - 1);
  const int b = bx >> (1 + LOGB);
  const int y0 = band * ROWS;
  const int tid = threadIdx.x;
  const int lane = tid & 63;
  const int w = tid >> 6;
  const int m15 = lane & 15;
  const int kg = lane >> 4;
  const int r = w & (ROWS - 1);
  const int hcg = (ROWS == 4) ? (w >> 2) : (w >> 1);

  // fragment read offsets (bytes), conflict-free via baked swizzle
  int offA[2][3][2];
  #pragma unroll
  for (int xh = 0; xh < 2; ++xh)
    #pragma unroll
    for (int kx = 0; kx < 3; ++kx)
      #pragma unroll
      for (int pl = 0; pl < 2; ++pl) {
        const int px = xh * 16 + kx + m15;
        const int sw = (pl * 4 + kg) ^ (px & 7);
        offA[xh][kx][pl] = r * ROWB + px * 128 + sw * 16;
      }
  int offW[2][4];
  {
    const int hcp = hcg * 8 + (m15 >> 1);
    const int b8 = kg + 4 * (m15 & 1);
    #pragma unroll
    for (int pl = 0; pl < 2; ++pl)
      #pragma unroll
      for (int g = 0; g < 4; ++g)
        offW[pl][g] = (((pl * 4 + g) * 16 + hcp) * 8 + (b8 ^ (hcp & 7))) * 16;
  }

  const int ncg = a.nc0 + a.nc1 + a.nc2;
  auto abase = [&](int cg) -> const char* {
    const uint16_t* t;
    if (cg < a.nc0) t = a.in0 + ((size_t)b * a.nc0 + cg) * IMG;
    else if (cg < a.nc0 + a.nc1) t = a.in1 + ((size_t)b * a.nc1 + (cg - a.nc0)) * IMG;
    else t = a.in2 + ((size_t)b * a.nc2 + (cg - a.nc0 - a.nc1)) * IMG;
    return (const char*)t + (size_t)y0 * ROWB;
  };
  // ACH chunks/wave (ROWS+2 rows used, tail lands in dead LDS; source has PADB slack)
  auto stageA = [&](int cgi, int par) {
    const char* g = abase(cgi);
    char* d = Asm_ + par * ASLOT;
    #pragma unroll
    for (int j = 0; j < ACH; ++j)
      gl_lds16(g + (size_t)(ACH * w + j) * 1024 + lane * 16, d + (ACH * w + j) * 1024);
  };
  // W: running wave-uniform source pointer (SALU increment), WCH chunks per 16 KB tile.
  const char* const wbeg = (const char*)a.W + (size_t)nt * 16384;
  const char* const wend = (const char*)a.W + (size_t)(ncg > 0 ? ncg : 1) * 9 * 32768;
  const char* wsrc = wbeg;
  auto stageW = [&](int slot) {
    char* d = Wsm_ + slot * 16384;
    #pragma unroll
    for (int j = 0; j < WCH; ++j)
      gl_lds16(wsrc + (size_t)(WCH * w + j) * 1024 + lane * 16, d + (WCH * w + j) * 1024);
    wsrc += 32768;
    if (wsrc >= wend) wsrc = wbeg;   // dummy restage near the tail (valid memory)
  };

  float4v acc[2][4];
  #pragma unroll
  for (int xh = 0; xh < 2; ++xh)
    #pragma unroll
    for (int g = 0; g < 4; ++g) acc[xh][g] = (float4v){0.f, 0.f, 0.f, 0.f};

  if (ncg > 0) {
    // Prologue: A[0] then W[0] -> slot0, W[1] -> slot1 (order matters for vmcnt math).
    stageA(0, 0);
    stageW(0);
    stageW(1);

    for (int cg = 0; cg < ncg; ++cg) {
      auto tap_body = [&](auto tapc) {
        constexpr int TAP = decltype(tapc)::v;
        constexpr int CNT = (TAP == 1 || TAP == 2) ? CNT12 : CNT0;
        constexpr int SLOT2 = (TAP + 2) % 3;   // slot of the tile staged now (lin+2)
        constexpr int SLOTR = TAP % 3;         // slot read this tap (lin%3 == TAP%3)
        asm volatile("s_waitcnt vmcnt(%0)\n\ts_barrier" :: "n"(CNT) : "memory");
        stageW(SLOT2);                         // wsrc tracks lin+2 linearly
        if (TAP == 0) {  // stage next cg's A into the other parity
          const int nx = (cg + 1 < ncg) ? cg + 1 : 0;
          stageA(nx, (cg + 1) & 1);
        }
        constexpr int ky = TAP / 3, kx = TAP % 3;
        const char* Ab = Asm_ + (cg & 1) * ASLOT + ky * ROWB;
        const char* Wb = Wsm_ + SLOTR * 16384;
        short8 af[2][2];
        #pragma unroll
        for (int xh = 0; xh < 2; ++xh)
          #pragma unroll
          for (int pl = 0; pl < 2; ++pl)
            af[xh][pl] = *(const short8*)(Ab + offA[xh][kx][pl]);
        short8 wfr[2][4];
        #pragma unroll
        for (int pl = 0; pl < 2; ++pl)
          #pragma unroll
          for (int g = 0; g < 4; ++g)
            wfr[pl][g] = *(const short8*)(Wb + offW[pl][g]);
        __builtin_amdgcn_s_setprio(1);
        #pragma unroll
        for (int xh = 0; xh < 2; ++xh)
          #pragma unroll
          for (int g = 0; g < 4; ++g) {
            acc[xh][g] = __builtin_amdgcn_mfma_f32_16x16x32_bf16(af[xh][0], wfr[0][g], acc[xh][g], 0, 0, 0);
            acc[xh][g] = __builtin_amdgcn_mfma_f32_16x16x32_bf16(af[xh][0], wfr[1][g], acc[xh][g], 0, 0, 0);
            acc[xh][g] = __builtin_amdgcn_mfma_f32_16x16x32_bf16(af[xh][1], wfr[0][g], acc[xh][g], 0, 0, 0);
          }
        __builtin_amdgcn_s_setprio(0);
      };
      tap_body(IC<0>{}); tap_body(IC<1>{}); tap_body(IC<2>{});
      tap_body(IC<3>{}); tap_body(IC<4>{}); tap_body(IC<5>{});
      tap_body(IC<6>{}); tap_body(IC<7>{}); tap_body(IC<8>{});
    }
    asm volatile("s_waitcnt vmcnt(0)" ::: "memory");  // drain dummy restages
  }

  // ---- fused LSTM cell epilogue ----
  const int hcl = hcg * 16 + m15;
  const int hc = nt * 32 + hcl;
  const int y = y0 + r;
  float bi[4];
  #pragma unroll
  for (int g = 0; g < 4; ++g) bi[g] = a.bias[g * 64 + hc];
  float* crow = a.cbuf + ((size_t)(b * 64 + hc)) * 1024 + y * 32;
  float* hrow = a.hf32 ? a.hf32 + ((size_t)(b * 64 + hc)) * 1024 + y * 32 : nullptr;
  uint16_t* hb = a.himg ? a.himg + ((size_t)(b * 2 + nt)) * IMG : nullptr;
  const int kgb = hcl >> 3, jj = hcl & 7;
  #pragma unroll
  for (int xh = 0; xh < 2; ++xh) {
    const int x0 = xh * 16 + kg * 4;
    float4v cv = *(float4v*)(crow + x0);
    float4v pre[4];
    if (a.gpre) {
      #pragma unroll
      for (int g = 0; g < 4; ++g)
        pre[g] = *(const float4v*)(a.gpre + ((size_t)(b * 256 + g * 64 + hc)) * 1024 + y * 32 + x0);
    } else {
      #pragma unroll
      for (int g = 0; g < 4; ++g) pre[g] = (float4v){bi[g], bi[g], bi[g], bi[g]};
    }
    float4v cn, hn;
    #pragma unroll
    for (int q = 0; q < 4; ++q) {
      const float ig = 1.f / (1.f + expf(-(acc[xh][0][q] + pre[0][q])));
      const float fg = 1.f / (1.f + expf(-(acc[xh][1][q] + pre[1][q])));
      const float gg = tanhf(acc[xh][2][q] + pre[2][q]);
      const float og = 1.f / (1.f + expf(-(acc[xh][3][q] + pre[3][q])));
      const float c2 = fg * cv[q] + ig * gg;
      cn[q] = c2;
      hn[q] = og * tanhf(c2);
    }
    *(float4v*)(crow + x0) = cn;
    if (hrow) *(float4v*)(hrow + x0) = hn;
    if (hb) {
      #pragma unroll
      for (int q = 0; q < 4; ++q) {
        const int px = x0 + q + 1;
        const int sw = px & 7;
        const uint16_t hi = bf16_rne(hn[q]);
        const uint16_t lo = bf16_rne(hn[q] - bf16_to_f(hi));
        const size_t p16 = ((size_t)(y + 1) * 34 + px) * 64;
        hb[p16 + (size_t)(kgb ^ sw) * 8 + jj] = hi;
        hb[p16 + (size_t)((4 + kgb) ^ sw) * 8 + jj] = lo;
      }
    }
  }
  if (hb) {   // keep image borders zero (ws is re-poisoned every call)
    {
      const int rr = tid >> 7;             // 0..ROWS-1 (THREADS = ROWS*128)
      const int hlf = (tid >> 6) & 1;
      const int jx = tid & 63;
      hb[((size_t)(y0 + 1 + rr) * 34 + hlf * 33) * 64 + jx] = 0;
    }
    if (band == 0) for (int i = tid; i < 2176; i += THREADS) hb[i] = 0;
    if (band == BANDS - 1) for (int i = tid; i < 2176; i += THREADS) hb[(size_t)33 * 2176 + i] = 0;
  }
}

// ---- batched layer-1 input projection: gpre[slot] = conv(xs1, W_ih1) + bias ----
// slot 0..7: fwd t (inputs hf0[t+1], hr0[t], combo 2); slot 8: rev (hf0[8], hr0[7], combo 3).
// ROWS=4 proven shape: grid (128, 9), 512 thr, LDS 114688. ncg=4 fixed (W_ih cgs 0..3).
struct PreArgs {
  const uint16_t* hf0i; const uint16_t* hr0i;
  const uint32_t* WP; const float* bp; float* gpre;
};
__global__ __launch_bounds__(512, 2) void conv_gates_pre(PreArgs P) {
  constexpr int ACH = 4, ASLOT = 32768, WCH = 2, CNT0 = 2, CNT12 = 6;
  extern __shared__ char smem[];
  char* Asm_ = smem;
  char* Wsm_ = smem + 65536;

  const int slot = blockIdx.y;
  const uint16_t* in0; const uint16_t* in1; const uint32_t* Wc; const float* bias;
  if (slot < 8) {
    in0 = P.hf0i + (size_t)(slot + 1) * SLOTI; in1 = P.hr0i + (size_t)slot * SLOTI;
    Wc = P.WP + (size_t)2 * 442368; bias = P.bp + 2 * 256;
  } else {
    in0 = P.hf0i + (size_t)8 * SLOTI; in1 = P.hr0i + (size_t)7 * SLOTI;
    Wc = P.WP + (size_t)3 * 442368; bias = P.bp + 3 * 256;
  }

  const int bx = blockIdx.x;
  const int nt = bx & 1;
  const int band = (bx >> 1) & 7;
  const int b = bx >> 4;
  const int y0 = band * 4;
  const int tid = threadIdx.x;
  const int lane = tid & 63;
  const int w = tid >> 6;
  const int m15 = lane & 15;
  const int kg = lane >> 4;
  const int r = w & 3;
  const int hcg = w >> 2;

  int offA[2][3][2];
  #pragma unroll
  for (int xh = 0; xh < 2; ++xh)
    #pragma unroll
    for (int kx = 0; kx < 3; ++kx)
      #pragma unroll
      for (int pl = 0; pl < 2; ++pl) {
        const int px = xh * 16 + kx + m15;
        const int sw = (pl * 4 + kg) ^ (px & 7);
        offA[xh][kx][pl] = r * ROWB + px * 128 + sw * 16;
      }
  int offW[2][4];
  {
    const int hcp = hcg * 8 + (m15 >> 1);
    const int b8 = kg + 4 * (m15 & 1);
    #pragma unroll
    for (int pl = 0; pl < 2; ++pl)
      #pragma unroll
      for (int g = 0; g < 4; ++g)
        offW[pl][g] = (((pl * 4 + g) * 16 + hcp) * 8 + (b8 ^ (hcp & 7))) * 16;
  }

  auto abase = [&](int cg) -> const char* {
    const uint16_t* t = (cg < 2) ? in0 + ((size_t)b * 2 + cg) * IMG
                                 : in1 + ((size_t)b * 2 + (cg - 2)) * IMG;
    return (const char*)t + (size_t)y0 * ROWB;
  };
  auto stageA = [&](int cgi, int par) {
    const char* g = abase(cgi);
    char* d = Asm_ + par * ASLOT;
    #pragma unroll
    for (int j = 0; j < ACH; ++j)
      gl_lds16(g + (size_t)(ACH * w + j) * 1024 + lane * 16, d + (ACH * w + j) * 1024);
  };
  const char* const wbeg = (const char*)Wc + (size_t)nt * 16384;
  const char* const wend = (const char*)Wc + (size_t)4 * 9 * 32768;
  const char* wsrc = wbeg;
  auto stageW = [&](int slotw) {
    char* d = Wsm_ + slotw * 16384;
    #pragma unroll
    for (int j = 0; j < WCH; ++j)
      gl_lds16(wsrc + (size_t)(WCH * w + j) * 1024 + lane * 16, d + (WCH * w + j) * 1024);
    wsrc += 32768;
    if (wsrc >= wend) wsrc = wbeg;
  };

  float4v acc[2][4];
  #pragma unroll
  for (int xh = 0; xh < 2; ++xh)
    #pragma unroll
    for (int g = 0; g < 4; ++g) acc[xh][g] = (float4v){0.f, 0.f, 0.f, 0.f};

  stageA(0, 0);
  stageW(0);
  stageW(1);

  for (int cg = 0; cg < 4; ++cg) {
    auto tap_body = [&](auto tapc) {
      constexpr int TAP = decltype(tapc)::v;
      constexpr int CNT = (TAP == 1 || TAP == 2) ? CNT12 : CNT0;
      constexpr int SLOT2 = (TAP + 2) % 3;
      constexpr int SLOTR = TAP % 3;
      asm volatile("s_waitcnt vmcnt(%0)\n\ts_barrier" :: "n"(CNT) : "memory");
      stageW(SLOT2);
      if (TAP == 0) {
        const int nx = (cg + 1 < 4) ? cg + 1 : 0;
        stageA(nx, (cg + 1) & 1);
      }
      constexpr int ky = TAP / 3, kx = TAP % 3;
      const char* Ab = Asm_ + (cg & 1) * ASLOT + ky * ROWB;
      const char* Wb = Wsm_ + SLOTR * 16384;
      short8 af[2][2];
      #pragma unroll
      for (int xh = 0; xh < 2; ++xh)
        #pragma unroll
        for (int pl = 0; pl < 2; ++pl)
          af[xh][pl] = *(const short8*)(Ab + offA[xh][kx][pl]);
      short8 wfr[2][4];
      #pragma unroll
      for (int pl = 0; pl < 2; ++pl)
        #pragma unroll
        for (int g = 0; g < 4; ++g)
          wfr[pl][g] = *(const short8*)(Wb + offW[pl][g]);
      __builtin_amdgcn_s_setprio(1);
      #pragma unroll
      for (int xh = 0; xh < 2; ++xh)
        #pragma unroll
        for (int g = 0; g < 4; ++g) {
          acc[xh][g] = __builtin_amdgcn_mfma_f32_16x16x32_bf16(af[xh][0], wfr[0][g], acc[xh][g], 0, 0, 0);
          acc[xh][g] = __builtin_amdgcn_mfma_f32_16x16x32_bf16(af[xh][0], wfr[1][g], acc[xh][g], 0, 0, 0);
          acc[xh][g] = __builtin_amdgcn_mfma_f32_16x16x32_bf16(af[xh][1], wfr[0][g], acc[xh][g], 0, 0, 0);
        }
      __builtin_amdgcn_s_setprio(0);
    };
    tap_body(IC<0>{}); tap_body(IC<1>{}); tap_body(IC<2>{});
    tap_body(IC<3>{}); tap_body(IC<4>{}); tap_body(IC<5>{});
    tap_body(IC<6>{}); tap_body(IC<7>{}); tap_body(IC<8>{});
  }
  asm volatile("s_waitcnt vmcnt(0)" ::: "memory");

  const int hcl = hcg * 16 + m15;
  const int hc = nt * 32 + hcl;
  const int y = y0 + r;
  float* gb = P.gpre + (size_t)slot * GSLOT + (size_t)b * 262144;
  #pragma unroll
  for (int xh = 0; xh < 2; ++xh) {
    const int x0 = xh * 16 + kg * 4;
    #pragma unroll
    for (int g = 0; g < 4; ++g) {
      float4v v = acc[xh][g];
      const float bv = bias[g * 64 + hc];
      #pragma unroll
      for (int q = 0; q < 4; ++q) v[q] += bv;
      *(float4v*)(gb + ((size_t)(g * 64 + hc)) * 1024 + y * 32 + x0) = v;
    }
  }
}

// out[b][o][p] = relu(b_out[o] + sum_c w_out[o][c] * last[b][c][p])  (fp32 inputs)
__global__ void final_conv(const float* __restrict__ h1f_last, const float* __restrict__ h1r_last,
                           const float* __restrict__ wout, const float* __restrict__ bout,
                           float* __restrict__ out) {
  __shared__ float Ws[16 * 128];
  const int oq = blockIdx.y;
  for (int i = threadIdx.x; i < 16 * 128; i += 256) Ws[i] = wout[oq * 16 * 128 + i];
  __syncthreads();
  const int gp = blockIdx.x * 256 + threadIdx.x;
  const int b = gp >> 10, p = gp & 1023;
  float acc[16];
  #pragma unroll
  for (int o = 0; o < 16; ++o) acc[o] = bout[oq * 16 + o];
  for (int c = 0; c < 128; ++c) {
    const float xv = (c < 64) ? h1f_last[((size_t)b * 64 + c) * 1024 + p]
                              : h1r_last[((size_t)b * 64 + (c - 64)) * 1024 + p];
    #pragma unroll
    for (int o = 0; o < 16; ++o) acc[o] = fmaf(xv, Ws[o * 128 + c], acc[o]);
  }
  #pragma unroll
  for (int o = 0; o < 16; ++o) {
    const float v = acc[o];
    out[((size_t)b * 64 + oq * 16 + o) * 1024 + p] = v > 0.f ? v : 0.f;
  }
}

extern "C" void kernel_launch(void* const* d_in, const int* in_sizes, int n_in,
                              void* d_out, int out_size, void* d_ws, size_t ws_size,
                              hipStream_t stream) {
  char* p = (char*)d_ws;
  uint16_t* featImg = (uint16_t*)p; p += (size_t)8 * 8 * 4 * IMG * 2 + PADB;  // 37.9 MB
  uint32_t* WP = (uint32_t*)p;      p += (size_t)4 * 442368 * 4;              // 7.1 MB
  float* bp = (float*)p;            p += 4096;
  uint16_t* hf0i = (uint16_t*)p;    p += (size_t)9 * SLOTI * 2 + PADB;        // 21.3 MB
  uint16_t* hr0i = (uint16_t*)p;    p += (size_t)9 * SLOTI * 2 + PADB;        // 21.3 MB
  uint16_t* h1fi = (uint16_t*)p;    p += (size_t)2 * SLOTI * 2 + PADB;        // 4.7 MB
  float* c0f = (float*)p;           p += (size_t)4 * 2097152;                 // c states
  float* c0r = c0f + 524288;
  float* c1f = c0r + 524288;
  float* c1r = c1f + 524288;
  float* h1f8 = (float*)p;          p += 2097152;
  float* h1r8 = (float*)p;          p += 2097152;
  float* gpre = (float*)p;          p += (size_t)9 * GSLOT * 4;               // 75.5 MB

  hipMemsetAsync(c0f, 0, (size_t)4 * 2097152, stream);   // all 4 c states

  pack_features<<<dim3(9248), 256, 0, stream>>>((const float*)d_in[0], featImg);

  WPackArgs wa;
  for (int combo = 0; combo < 4; ++combo) {
    const int base = 1 + combo * 4;
    wa.wih[combo] = (const float*)d_in[base];
    wa.whh[combo] = (const float*)d_in[base + 1];
    wa.bih[combo] = (const float*)d_in[base + 2];
    wa.bhh[combo] = (const float*)d_in[base + 3];
  }
  wa.wp = WP; wa.bp = bp;
  pack_weights<<<dim3(1728, 4), 256, 0, stream>>>(wa);

  constexpr int DYN4 = 2 * 32768 + 3 * 16384;   // 114688: ROWS=4
  constexpr int DYN2 = 2 * 20480 + 3 * 16384;   // 90112:  ROWS=2
  (void)hipFuncSetAttribute((const void*)(conv_lstm_step<4>),
                            hipFuncAttributeMaxDynamicSharedMemorySize, DYN4);
  (void)hipFuncSetAttribute((const void*)(conv_lstm_step<2>),
                            hipFuncAttributeMaxDynamicSharedMemorySize, DYN2);
  (void)hipFuncSetAttribute((const void*)conv_gates_pre,
                            hipFuncAttributeMaxDynamicSharedMemorySize, DYN4);

  auto mk = [&](const uint16_t* i0, int n0, const uint16_t* i1, int n1,
                const uint16_t* i2, int n2, int combo, int cgskip, float* cb,
                uint16_t* himg, float* hf32, const float* gp) {
    StepArgs s;
    s.in0 = i0; s.in1 = i1; s.in2 = i2;
    s.nc0 = n0; s.nc1 = n1; s.nc2 = n2;
    s.W = WP + (size_t)combo * 442368 + (size_t)cgskip * CGU32;
    s.bias = bp + combo * 256;
    s.gpre = gp; s.cbuf = cb; s.himg = himg; s.hf32 = hf32;
    return s;
  };

  // Layer 0: 8 pair launches (fwd step k, rev step 7-k); 128 blocks/dir, 512 thr.
  // Round 0 drops the zero-h cgs (ncg=4): h init is zero -> conv(h)=0.
  for (int k = 0; k < 8; ++k) {
    const int tr = 7 - k;
    StepArgs f = (k == 0)
        ? mk(featImg, 4, nullptr, 0, nullptr, 0,
             0, 0, c0f, hf0i + (size_t)1 * SLOTI, nullptr, nullptr)
        : mk(featImg + (size_t)k * 8 * 4 * IMG, 4,
             hf0i + (size_t)k * SLOTI, 2, nullptr, 0,
             0, 0, c0f, hf0i + (size_t)(k + 1) * SLOTI, nullptr, nullptr);
    StepArgs r = (k == 0)
        ? mk(featImg + (size_t)7 * 8 * 4 * IMG, 4, nullptr, 0, nullptr, 0,
             1, 0, c0r, hr0i + (size_t)7 * SLOTI, nullptr, nullptr)
        : mk(featImg + (size_t)tr * 8 * 4 * IMG, 4,
             hr0i + (size_t)(tr + 1) * SLOTI, 2, nullptr, 0,
             1, 0, c0r, hr0i + (size_t)tr * SLOTI, nullptr, nullptr);
    conv_lstm_step<4><<<dim3(128, 1, 2), 512, DYN4, stream>>>(f, r);
  }

  // Batched layer-1 input projections (+ bias): gpre slots 0..7 fwd, 8 rev.
  PreArgs pa; pa.hf0i = hf0i; pa.hr0i = hr0i; pa.WP = WP; pa.bp = bp; pa.gpre = gpre;
  conv_gates_pre<<<dim3(128, 9), 512, DYN4, stream>>>(pa);

  // Layer 1 t=0 fwd and the rev step: h init zero -> pure LSTM cell on gpre (ncg=0).
  {
    StepArgs f0 = mk(nullptr, 0, nullptr, 0, nullptr, 0,
                     2, 0, c1f, h1fi + (size_t)1 * SLOTI, nullptr, gpre);
    StepArgs rv = mk(nullptr, 0, nullptr, 0, nullptr, 0,
                     3, 0, c1r, nullptr, h1r8, gpre + (size_t)8 * GSLOT);
    conv_lstm_step<4><<<dim3(128, 1, 2), 512, DYN4, stream>>>(f0, rv);
  }

  // Layer 1 fwd t=1..7: h-recurrence only (ncg=2, W base at cg4 = W_hh taps) + gpre.
  for (int t = 1; t < 8; ++t) {
    uint16_t* himg = (t < 7) ? h1fi + (size_t)((t + 1) & 1) * SLOTI : nullptr;
    float* hf32 = (t == 7) ? h1f8 : nullptr;
    StepArgs s = mk(h1fi + (size_t)(t & 1) * SLOTI, 2, nullptr, 0, nullptr, 0,
                    2, 4, c1f, himg, hf32, gpre + (size_t)t * GSLOT);
    conv_lstm_step<2><<<dim3(256, 1, 1), 256, DYN2, stream>>>(s, s);
  }

  final_conv<<<dim3(32, 4), 256, 0, stream>>>(
      h1f8, h1r8, (const float*)d_in[17], (const float*)d_in[18], (float*)d_out);
}